// Round 2
// baseline (1288.932 us; speedup 1.0000x reference)
//
#include <hip/hip_runtime.h>
#include <hip/hip_bf16.h>

// ---------------- problem constants ----------------
#define B 8
#define TL 512
#define M_ROWS 4096
#define D 1024
#define DFF 1024
#define H 8
#define DH 128
#define NL 6

typedef unsigned short ushort_t;
typedef unsigned int uint_t;
typedef short bf16x8 __attribute__((ext_vector_type(8)));
typedef float f32x4 __attribute__((ext_vector_type(4)));

__device__ __forceinline__ ushort_t f2bf(float f) {
    uint_t u = __float_as_uint(f);
    u += 0x7FFFu + ((u >> 16) & 1u);
    return (ushort_t)(u >> 16);
}
__device__ __forceinline__ float gelu_exact(float x) {
    return 0.5f * x * (1.0f + erff(x * 0.70710678118654752f));
}
__device__ __forceinline__ void gload_lds16(const ushort_t* g, ushort_t* l) {
    __builtin_amdgcn_global_load_lds(
        (const __attribute__((address_space(1))) void*)g,
        (__attribute__((address_space(3))) void*)l, 16, 0, 0);
}
// counted-wait + raw barrier (no compiler vmcnt(0) drain except where we say so)
__device__ __forceinline__ void gsync_drain() {
    asm volatile("s_waitcnt vmcnt(0) lgkmcnt(0)" ::: "memory");
    __builtin_amdgcn_sched_barrier(0);
    __builtin_amdgcn_s_barrier();
}

// ---------------- f32 -> bf16 conversion, block-partitioned ----------------
struct CvtArgs {
    const float* s[7];
    ushort_t* d[7];
    int nq[7];      // float4-chunk counts
    int bstart[8];  // block ranges per segment
};

__global__ __launch_bounds__(256) void cvt_all(CvtArgs a) {
    const int bid = blockIdx.x;
#pragma unroll
    for (int seg = 0; seg < 7; ++seg) {
        const int b0 = a.bstart[seg], b1 = a.bstart[seg + 1];
        if (bid < b0 || bid >= b1) continue;
        const int stride = (b1 - b0) * 256;
        const float* s = a.s[seg];
        ushort_t* d = a.d[seg];
        const int nq = a.nq[seg];
        for (int i = (bid - b0) * 256 + threadIdx.x; i < nq; i += stride) {
            float4 v = *(const float4*)(s + (size_t)i * 4);
            ushort4 o;
            o.x = f2bf(v.x); o.y = f2bf(v.y); o.z = f2bf(v.z); o.w = f2bf(v.w);
            *(ushort4*)(d + (size_t)i * 4) = o;
        }
    }
}

// LDS row = 8 chunks of 16B (BK=64 bf16); XOR swizzle baked into staging.
#define LSLOT64(r, c) (((r) * 8 + ((c) ^ ((r) & 7))) * 8)

// ---------------- N=1024 GEMM: 128Mx64N tile, BK=64, 2-phase dbuf ----------
__global__ __launch_bounds__(256) void gemm_n64(
    const ushort_t* __restrict__ A, const ushort_t* __restrict__ W,
    const float* __restrict__ bias, float* __restrict__ Cf,
    ushort_t* __restrict__ Cb, int M, int N, int K, int do_gelu) {
    __shared__ ushort_t As[2][128 * 64];  // 2 x 16 KB
    __shared__ ushort_t Bs[2][64 * 64];   // 2 x 8 KB

    const int tid = threadIdx.x;
    const int lane = tid & 63;
    const int w = tid >> 6;
    const int wm = (w & 2) * 32;
    const int wn = (w & 1) * 32;
    const int bm = blockIdx.y * 128;
    const int bn = blockIdx.x * 64;

    const ushort_t* gA[4];
    int sA[4];
#pragma unroll
    for (int t = 0; t < 4; ++t) {
        int s = tid + t * 256;
        int r = s >> 3, gl = (s & 7) ^ (r & 7);
        gA[t] = A + (size_t)(bm + r) * K + gl * 8;
        sA[t] = s * 8;
    }
    const ushort_t* gB[2];
    int sB[2];
#pragma unroll
    for (int t = 0; t < 2; ++t) {
        int s = tid + t * 256;
        int r = s >> 3, gl = (s & 7) ^ (r & 7);
        gB[t] = W + (size_t)(bn + r) * K + gl * 8;
        sB[t] = s * 8;
    }

    const int fr = lane & 15;
    const int fq = lane >> 4;
    int aoff[4][2], boff[2][2];
#pragma unroll
    for (int t = 0; t < 4; ++t)
#pragma unroll
        for (int s = 0; s < 2; ++s)
            aoff[t][s] = LSLOT64(wm + t * 16 + fr, s * 4 + fq);
#pragma unroll
    for (int t = 0; t < 2; ++t)
#pragma unroll
        for (int s = 0; s < 2; ++s)
            boff[t][s] = LSLOT64(wn + t * 16 + fr, s * 4 + fq);

    f32x4 acc[4][2];
#pragma unroll
    for (int i = 0; i < 4; ++i)
#pragma unroll
        for (int j = 0; j < 2; ++j) acc[i][j] = (f32x4){0.f, 0.f, 0.f, 0.f};

    auto stage = [&](int buf, int k0) {
#pragma unroll
        for (int t = 0; t < 4; ++t) gload_lds16(gA[t] + k0, &As[buf][sA[t]]);
#pragma unroll
        for (int t = 0; t < 2; ++t) gload_lds16(gB[t] + k0, &Bs[buf][sB[t]]);
    };
    auto comp = [&](int buf) {
#pragma unroll
        for (int s = 0; s < 2; ++s) {
            bf16x8 af[4], bfv[2];
#pragma unroll
            for (int t = 0; t < 4; ++t)
                af[t] = *(const bf16x8*)&As[buf][aoff[t][s]];
#pragma unroll
            for (int t = 0; t < 2; ++t)
                bfv[t] = *(const bf16x8*)&Bs[buf][boff[t][s]];
#pragma unroll
            for (int i = 0; i < 4; ++i)
#pragma unroll
                for (int j = 0; j < 2; ++j)
                    acc[i][j] = __builtin_amdgcn_mfma_f32_16x16x32_bf16(
                        af[i], bfv[j], acc[i][j], 0, 0, 0);
        }
    };

    stage(0, 0);
    gsync_drain();
    for (int k0 = 0; k0 < K; k0 += 128) {  // K is a multiple of 128
        stage(1, k0 + 64);
        comp(0);
        gsync_drain();
        if (k0 + 128 < K) stage(0, k0 + 128);
        comp(1);
        gsync_drain();
    }

#pragma unroll
    for (int tj = 0; tj < 2; ++tj) {
        const int n = bn + wn + tj * 16 + fr;
        const float bv = bias[n];
#pragma unroll
        for (int ti = 0; ti < 4; ++ti) {
            const int m0 = bm + wm + ti * 16 + fq * 4;
            f32x4 a = acc[ti][tj];
#pragma unroll
            for (int r = 0; r < 4; ++r) {
                float v = a[r] + bv;
                if (do_gelu) v = gelu_exact(v);
                const size_t off = (size_t)(m0 + r) * N + n;
                if (Cf) Cf[off] = v;
                if (Cb) Cb[off] = f2bf(v);
            }
        }
    }
}

// ---------------- QKV GEMM: 128x128 tile, BK=64, 2-phase dbuf --------------
__global__ __launch_bounds__(256) void gemm_qkv(
    const ushort_t* __restrict__ A, const ushort_t* __restrict__ W,
    const float* __restrict__ bias, ushort_t* __restrict__ Qb,
    ushort_t* __restrict__ Kb, ushort_t* __restrict__ Vt, int K) {
    __shared__ ushort_t As[2][128 * 64];  // 2 x 16 KB
    __shared__ ushort_t Bs[2][128 * 64];  // 2 x 16 KB

    const int tid = threadIdx.x;
    const int lane = tid & 63;
    const int w = tid >> 6;
    const int wm = (w >> 1) * 64;
    const int wn = (w & 1) * 64;
    const int bm = blockIdx.y * 128;
    const int bn = blockIdx.x * 128;

    const ushort_t* gA[4];
    const ushort_t* gB[4];
    int sAB[4];
#pragma unroll
    for (int t = 0; t < 4; ++t) {
        int s = tid + t * 256;
        int r = s >> 3, gl = (s & 7) ^ (r & 7);
        gA[t] = A + (size_t)(bm + r) * K + gl * 8;
        gB[t] = W + (size_t)(bn + r) * K + gl * 8;
        sAB[t] = s * 8;
    }

    const int fr = lane & 15;
    const int fq = lane >> 4;
    int aoff[4][2], boff[4][2];
#pragma unroll
    for (int t = 0; t < 4; ++t)
#pragma unroll
        for (int s = 0; s < 2; ++s) {
            aoff[t][s] = LSLOT64(wm + t * 16 + fr, s * 4 + fq);
            boff[t][s] = LSLOT64(wn + t * 16 + fr, s * 4 + fq);
        }

    f32x4 acc[4][4];
#pragma unroll
    for (int i = 0; i < 4; ++i)
#pragma unroll
        for (int j = 0; j < 4; ++j) acc[i][j] = (f32x4){0.f, 0.f, 0.f, 0.f};

    auto stage = [&](int buf, int k0) {
#pragma unroll
        for (int t = 0; t < 4; ++t) gload_lds16(gA[t] + k0, &As[buf][sAB[t]]);
#pragma unroll
        for (int t = 0; t < 4; ++t) gload_lds16(gB[t] + k0, &Bs[buf][sAB[t]]);
    };
    auto comp = [&](int buf) {
#pragma unroll
        for (int s = 0; s < 2; ++s) {
            bf16x8 af[4], bfv[4];
#pragma unroll
            for (int t = 0; t < 4; ++t)
                af[t] = *(const bf16x8*)&As[buf][aoff[t][s]];
#pragma unroll
            for (int t = 0; t < 4; ++t)
                bfv[t] = *(const bf16x8*)&Bs[buf][boff[t][s]];
#pragma unroll
            for (int i = 0; i < 4; ++i)
#pragma unroll
                for (int j = 0; j < 4; ++j)
                    acc[i][j] = __builtin_amdgcn_mfma_f32_16x16x32_bf16(
                        af[i], bfv[j], acc[i][j], 0, 0, 0);
        }
    };

    stage(0, 0);
    gsync_drain();
    for (int k0 = 0; k0 < K; k0 += 128) {  // K = 1024
        stage(1, k0 + 64);
        comp(0);
        gsync_drain();
        if (k0 + 128 < K) stage(0, k0 + 128);
        comp(1);
        gsync_drain();
    }

    const float qscale = 0.08838834764831845f;
#pragma unroll
    for (int tj = 0; tj < 4; ++tj) {
        const int n = bn + wn + tj * 16 + fr;
        const float bv = bias[n];
#pragma unroll
        for (int ti = 0; ti < 4; ++ti) {
            const int m0 = bm + wm + ti * 16 + fq * 4;
            f32x4 a = acc[ti][tj];
            if (n < D) {
#pragma unroll
                for (int r = 0; r < 4; ++r)
                    Qb[(size_t)(m0 + r) * D + n] = f2bf((a[r] + bv) * qscale);
            } else if (n < 2 * D) {
#pragma unroll
                for (int r = 0; r < 4; ++r)
                    Kb[(size_t)(m0 + r) * D + (n - D)] = f2bf(a[r] + bv);
            } else {
                const int h = (n - 2 * D) >> 7;
                const int dh = (n - 2 * D) & 127;
                const int bb = m0 >> 9;
                const int t = m0 & 511;
                ushort4 pk;
                pk.x = f2bf(a[0] + bv); pk.y = f2bf(a[1] + bv);
                pk.z = f2bf(a[2] + bv); pk.w = f2bf(a[3] + bv);
                *(ushort4*)&Vt[((size_t)(bb * H + h) * DH + dh) * TL + t] = pk;
            }
        }
    }
}

// ---------------- MFMA flash attention -------------------------------------
#define LSW16(r, g) ((((r) << 4) + ((g) ^ ((r) & 7))) << 3)
#define LSW8(r, g) ((((r) << 3) + ((g) ^ ((r) & 7))) << 3)

__global__ __launch_bounds__(256, 2) void attn_mfma(
    const ushort_t* __restrict__ Qb, const ushort_t* __restrict__ Kb,
    const ushort_t* __restrict__ Vt, ushort_t* __restrict__ Ab) {
    __shared__ ushort_t Qs[64 * 128];
    __shared__ ushort_t Ks[64 * 128];
    __shared__ ushort_t Vts[128 * 64];
    __shared__ ushort_t Ps[64 * 72];

    const int q0 = blockIdx.x * 64;
    const int bh = blockIdx.y;
    const int b = bh >> 3;
    const int h = bh & 7;
    const int tid = threadIdx.x;
    const int lane = tid & 63;
    const int w = tid >> 6;
    const int fr = lane & 15;
    const int fq = lane >> 4;

    const float slope = exp2f(-(float)(h + 1));

#pragma unroll
    for (int kk = 0; kk < 4; ++kk) {
        int s = tid + kk * 256;
        int r = s >> 4, gp = s & 15, gl = gp ^ (r & 7);
        gload_lds16(Qb + (size_t)(b * TL + q0 + r) * D + h * DH + gl * 8,
                    &Qs[s * 8]);
    }

    f32x4 o8[8];
    float m_i[4], l_i[4];
#pragma unroll
    for (int nt = 0; nt < 8; ++nt) o8[nt] = (f32x4){0.f, 0.f, 0.f, 0.f};
#pragma unroll
    for (int r = 0; r < 4; ++r) { m_i[r] = -1e30f; l_i[r] = 0.f; }

    for (int kt = 0; kt < TL / 64; ++kt) {
        __syncthreads();
#pragma unroll
        for (int kk = 0; kk < 4; ++kk) {
            int s = tid + kk * 256;
            int r = s >> 4, gp = s & 15, gl = gp ^ (r & 7);
            gload_lds16(Kb + (size_t)(b * TL + kt * 64 + r) * D + h * DH + gl * 8,
                        &Ks[s * 8]);
        }
#pragma unroll
        for (int kk = 0; kk < 4; ++kk) {
            int s = tid + kk * 256;
            int r = s >> 3, gp = s & 7, gl = gp ^ (r & 7);
            gload_lds16(Vt + ((size_t)bh * DH + r) * TL + kt * 64 + gl * 8,
                        &Vts[s * 8]);
        }
        __syncthreads();

        f32x4 sacc[4];
#pragma unroll
        for (int jt = 0; jt < 4; ++jt) sacc[jt] = (f32x4){0.f, 0.f, 0.f, 0.f};
#pragma unroll
        for (int s4 = 0; s4 < 4; ++s4) {
            bf16x8 aq = *(const bf16x8*)&Qs[LSW16(w * 16 + fr, s4 * 4 + fq)];
#pragma unroll
            for (int jt = 0; jt < 4; ++jt) {
                bf16x8 kb = *(const bf16x8*)&Ks[LSW16(jt * 16 + fr, s4 * 4 + fq)];
                sacc[jt] = __builtin_amdgcn_mfma_f32_16x16x32_bf16(
                    aq, kb, sacc[jt], 0, 0, 0);
            }
        }

        const int iq = q0 + w * 16 + fq * 4;
        const int jk = kt * 64 + fr;
        float al[4];
#pragma unroll
        for (int r = 0; r < 4; ++r) {
            float sv[4];
#pragma unroll
            for (int jt = 0; jt < 4; ++jt)
                sv[jt] = sacc[jt][r] -
                         slope * fabsf((float)(iq + r - jk - jt * 16));
            float mx = fmaxf(fmaxf(sv[0], sv[1]), fmaxf(sv[2], sv[3]));
            mx = fmaxf(mx, __shfl_xor(mx, 1));
            mx = fmaxf(mx, __shfl_xor(mx, 2));
            mx = fmaxf(mx, __shfl_xor(mx, 4));
            mx = fmaxf(mx, __shfl_xor(mx, 8));
            float mnew = fmaxf(m_i[r], mx);
            al[r] = __expf(m_i[r] - mnew);
            float rs = 0.f;
#pragma unroll
            for (int jt = 0; jt < 4; ++jt) {
                sv[jt] = __expf(sv[jt] - mnew);
                rs += sv[jt];
            }
            rs += __shfl_xor(rs, 1);
            rs += __shfl_xor(rs, 2);
            rs += __shfl_xor(rs, 4);
            rs += __shfl_xor(rs, 8);
            l_i[r] = l_i[r] * al[r] + rs;
            m_i[r] = mnew;
            const int prow = w * 16 + fq * 4 + r;
#pragma unroll
            for (int jt = 0; jt < 4; ++jt)
                Ps[prow * 72 + jt * 16 + fr] = f2bf(sv[jt]);
        }
#pragma unroll
        for (int nt = 0; nt < 8; ++nt)
#pragma unroll
            for (int r = 0; r < 4; ++r) o8[nt][r] *= al[r];

#pragma unroll
        for (int s2 = 0; s2 < 2; ++s2) {
            bf16x8 pa = *(const bf16x8*)&Ps[(w * 16 + fr) * 72 + s2 * 32 + fq * 8];
#pragma unroll
            for (int nt = 0; nt < 8; ++nt) {
                bf16x8 vb = *(const bf16x8*)&Vts[LSW8(nt * 16 + fr, s2 * 4 + fq)];
                o8[nt] = __builtin_amdgcn_mfma_f32_16x16x32_bf16(
                    pa, vb, o8[nt], 0, 0, 0);
            }
        }
    }

#pragma unroll
    for (int r = 0; r < 4; ++r) {
        float inv = 1.f / l_i[r];
        const size_t base = (size_t)(b * TL + q0 + w * 16 + fq * 4 + r) * D + h * DH;
#pragma unroll
        for (int nt = 0; nt < 8; ++nt)
            Ab[base + nt * 16 + fr] = f2bf(o8[nt][r] * inv);
    }
}

// ---------------- fused residual + LayerNorm, one wave per row -------------
// out = LN(x + y); no LDS, no barriers; 4 rows per 256-thread block.
__global__ __launch_bounds__(256) void add_ln(const float* __restrict__ x,
                                              const float* __restrict__ y,
                                              const float* __restrict__ g,
                                              const float* __restrict__ bta,
                                              float* __restrict__ out,
                                              ushort_t* __restrict__ outb) {
    const int row = blockIdx.x * 4 + (threadIdx.x >> 6);
    const int lane = threadIdx.x & 63;
    const size_t rbase = (size_t)row * D;

    float4 v[4];
#pragma unroll
    for (int j = 0; j < 4; ++j) {
        float4 xv = *(const float4*)(x + rbase + lane * 4 + j * 256);
        float4 yv = *(const float4*)(y + rbase + lane * 4 + j * 256);
        v[j].x = xv.x + yv.x; v[j].y = xv.y + yv.y;
        v[j].z = xv.z + yv.z; v[j].w = xv.w + yv.w;
    }

    float s = 0.f;
#pragma unroll
    for (int j = 0; j < 4; ++j) s += v[j].x + v[j].y + v[j].z + v[j].w;
#pragma unroll
    for (int off = 32; off; off >>= 1) s += __shfl_xor(s, off);
    const float mean = s * (1.f / (float)D);

    float sq = 0.f;
#pragma unroll
    for (int j = 0; j < 4; ++j) {
        float d0 = v[j].x - mean, d1 = v[j].y - mean;
        float d2 = v[j].z - mean, d3 = v[j].w - mean;
        sq += d0 * d0 + d1 * d1 + d2 * d2 + d3 * d3;
    }
#pragma unroll
    for (int off = 32; off; off >>= 1) sq += __shfl_xor(sq, off);
    const float var = sq * (1.f / (float)D);
    const float inv = rsqrtf(var + 1e-5f);

#pragma unroll
    for (int j = 0; j < 4; ++j) {
        const int col = lane * 4 + j * 256;
        float4 gv = *(const float4*)(g + col);
        float4 bv = *(const float4*)(bta + col);
        float4 o;
        o.x = (v[j].x - mean) * inv * gv.x + bv.x;
        o.y = (v[j].y - mean) * inv * gv.y + bv.y;
        o.z = (v[j].z - mean) * inv * gv.z + bv.z;
        o.w = (v[j].w - mean) * inv * gv.w + bv.w;
        *(float4*)(out + rbase + col) = o;
        ushort4 ob;
        ob.x = f2bf(o.x); ob.y = f2bf(o.y); ob.z = f2bf(o.z); ob.w = f2bf(o.w);
        *(ushort4*)(outb + rbase + col) = ob;
    }
}

// ---------------- launcher -------------------------------------------------
extern "C" void kernel_launch(void* const* d_in, const int* in_sizes, int n_in,
                              void* d_out, int out_size, void* d_ws, size_t ws_size,
                              hipStream_t stream) {
    const float* x_in   = (const float*)d_in[0];
    const float* pre_w  = (const float*)d_in[1];
    const float* pre_b  = (const float*)d_in[2];
    const float* in_w   = (const float*)d_in[3];
    const float* in_b   = (const float*)d_in[4];
    const float* out_w  = (const float*)d_in[5];
    const float* out_b  = (const float*)d_in[6];
    const float* ln1_g  = (const float*)d_in[7];
    const float* ln1_b  = (const float*)d_in[8];
    const float* ff1_w  = (const float*)d_in[9];
    const float* ff1_b  = (const float*)d_in[10];
    const float* ff2_w  = (const float*)d_in[11];
    const float* ff2_b  = (const float*)d_in[12];
    const float* ln2_g  = (const float*)d_in[13];
    const float* ln2_b  = (const float*)d_in[14];
    const float* post_w = (const float*)d_in[15];
    const float* post_b = (const float*)d_in[16];

    float* X = (float*)d_ws;
    float* Y = X + (size_t)M_ROWS * D;
    ushort_t* Xb   = (ushort_t*)(Y + (size_t)M_ROWS * D);
    ushort_t* Ab   = Xb + (size_t)M_ROWS * D;
    ushort_t* Qb   = Ab + (size_t)M_ROWS * D;
    ushort_t* Kb   = Qb + (size_t)M_ROWS * D;
    ushort_t* Vt   = Kb + (size_t)M_ROWS * D;
    ushort_t* xinb = Vt + (size_t)M_ROWS * D;
    ushort_t* pwb  = xinb + (size_t)M_ROWS * 512;
    ushort_t* iwb  = pwb + (size_t)D * 512;
    ushort_t* owb  = iwb + (size_t)NL * 3 * D * D;
    ushort_t* f1wb = owb + (size_t)NL * D * D;
    ushort_t* f2wb = f1wb + (size_t)NL * DFF * D;
    ushort_t* powb = f2wb + (size_t)NL * D * DFF;

    const dim3 blk(256);

    CvtArgs ca;
    ca.s[0] = x_in;   ca.d[0] = xinb; ca.nq[0] = (M_ROWS * 512) / 4;
    ca.s[1] = pre_w;  ca.d[1] = pwb;  ca.nq[1] = (D * 512) / 4;
    ca.s[2] = in_w;   ca.d[2] = iwb;  ca.nq[2] = (NL * 3 * D * D) / 4;
    ca.s[3] = out_w;  ca.d[3] = owb;  ca.nq[3] = (NL * D * D) / 4;
    ca.s[4] = ff1_w;  ca.d[4] = f1wb; ca.nq[4] = (NL * DFF * D) / 4;
    ca.s[5] = ff2_w;  ca.d[5] = f2wb; ca.nq[5] = (NL * D * DFF) / 4;
    ca.s[6] = post_w; ca.d[6] = powb; ca.nq[6] = (D * D) / 4;
    {
        long long total = 0;
        for (int i = 0; i < 7; ++i) total += ca.nq[i];
        long long cum = 0;
        ca.bstart[0] = 0;
        for (int i = 0; i < 7; ++i) {
            cum += ca.nq[i];
            ca.bstart[i + 1] = (int)((cum * 4096) / total);
        }
        ca.bstart[7] = 4096;
    }
    cvt_all<<<4096, blk, 0, stream>>>(ca);

    const dim3 gN64(D / 64, M_ROWS / 128);          // 512 blocks
    const dim3 gQKV(3 * D / 128, M_ROWS / 128);     // 768 blocks

    gemm_n64<<<gN64, blk, 0, stream>>>(xinb, pwb, pre_b, X, Xb,
                                       M_ROWS, D, 512, 0);

    for (int l = 0; l < NL; ++l) {
        gemm_qkv<<<gQKV, blk, 0, stream>>>(Xb, iwb + (size_t)l * 3 * D * D,
                                           in_b + (size_t)l * 3 * D,
                                           Qb, Kb, Vt, D);
        attn_mfma<<<dim3(TL / 64, B * H), blk, 0, stream>>>(Qb, Kb, Vt, Ab);
        gemm_n64<<<gN64, blk, 0, stream>>>(Ab, owb + (size_t)l * D * D,
                                           out_b + (size_t)l * D, Y, nullptr,
                                           M_ROWS, D, D, 0);
        add_ln<<<dim3(M_ROWS / 4), blk, 0, stream>>>(X, Y, ln1_g + (size_t)l * D,
                                                     ln1_b + (size_t)l * D, X, Xb);
        gemm_n64<<<gN64, blk, 0, stream>>>(Xb, f1wb + (size_t)l * DFF * D,
                                           ff1_b + (size_t)l * DFF, nullptr, Ab,
                                           M_ROWS, DFF, D, 1);
        gemm_n64<<<gN64, blk, 0, stream>>>(Ab, f2wb + (size_t)l * D * DFF,
                                           ff2_b + (size_t)l * D, Y, nullptr,
                                           M_ROWS, D, DFF, 0);
        add_ln<<<dim3(M_ROWS / 4), blk, 0, stream>>>(X, Y, ln2_g + (size_t)l * D,
                                                     ln2_b + (size_t)l * D, X, Xb);
    }

    gemm_n64<<<gN64, blk, 0, stream>>>(Xb, powb, post_b, (float*)d_out, nullptr,
                                       M_ROWS, D, D, 0);
}

// Round 3
// 1131.477 us; speedup vs baseline: 1.1392x; 1.1392x over previous
//
#include <hip/hip_runtime.h>
#include <hip/hip_bf16.h>

// ---------------- problem constants ----------------
#define B 8
#define TL 512
#define M_ROWS 4096
#define D 1024
#define DFF 1024
#define H 8
#define DH 128
#define NL 6

typedef unsigned short ushort_t;
typedef unsigned int uint_t;
typedef short bf16x8 __attribute__((ext_vector_type(8)));
typedef float f32x4 __attribute__((ext_vector_type(4)));

__device__ __forceinline__ ushort_t f2bf(float f) {
    uint_t u = __float_as_uint(f);
    u += 0x7FFFu + ((u >> 16) & 1u);
    return (ushort_t)(u >> 16);
}
__device__ __forceinline__ float gelu_exact(float x) {
    return 0.5f * x * (1.0f + erff(x * 0.70710678118654752f));
}
__device__ __forceinline__ void gload_lds16(const ushort_t* g, ushort_t* l) {
    __builtin_amdgcn_global_load_lds(
        (const __attribute__((address_space(1))) void*)g,
        (__attribute__((address_space(3))) void*)l, 16, 0, 0);
}

// ---------------- f32 -> bf16 conversion, block-partitioned ----------------
struct CvtArgs {
    const float* s[7];
    ushort_t* d[7];
    int nq[7];      // float4-chunk counts
    int bstart[8];  // block ranges per segment
};

__global__ __launch_bounds__(256) void cvt_all(CvtArgs a) {
    const int bid = blockIdx.x;
#pragma unroll
    for (int seg = 0; seg < 7; ++seg) {
        const int b0 = a.bstart[seg], b1 = a.bstart[seg + 1];
        if (bid < b0 || bid >= b1) continue;
        const int stride = (b1 - b0) * 256;
        const float* s = a.s[seg];
        ushort_t* d = a.d[seg];
        const int nq = a.nq[seg];
        for (int i = (bid - b0) * 256 + threadIdx.x; i < nq; i += stride) {
            float4 v = *(const float4*)(s + (size_t)i * 4);
            ushort4 o;
            o.x = f2bf(v.x); o.y = f2bf(v.y); o.z = f2bf(v.z); o.w = f2bf(v.w);
            *(ushort4*)(d + (size_t)i * 4) = o;
        }
    }
}

// LDS row = 8 chunks of 16B (BK=64 bf16); XOR swizzle baked into staging.
#define LSLOT64(r, c) (((r) * 8 + ((c) ^ ((r) & 7))) * 8)

// ---------------- N=1024 GEMM: 128Mx64N tile, BK=64 (R0 structure) ---------
__global__ __launch_bounds__(256) void gemm_n64(
    const ushort_t* __restrict__ A, const ushort_t* __restrict__ W,
    const float* __restrict__ bias, float* __restrict__ Cf,
    ushort_t* __restrict__ Cb, int M, int N, int K, int do_gelu) {
    __shared__ ushort_t As[128 * 64];  // 16 KB
    __shared__ ushort_t Bs[64 * 64];   // 8 KB

    const int tid = threadIdx.x;
    const int lane = tid & 63;
    const int w = tid >> 6;
    const int wm = (w & 2) * 32;
    const int wn = (w & 1) * 32;
    const int bm = blockIdx.y * 128;
    const int bn = blockIdx.x * 64;

    const ushort_t* gA[4];
    ushort_t* lA[4];
#pragma unroll
    for (int t = 0; t < 4; ++t) {
        int s = tid + t * 256;
        int r = s >> 3, gl = (s & 7) ^ (r & 7);
        gA[t] = A + (size_t)(bm + r) * K + gl * 8;
        lA[t] = &As[s * 8];
    }
    const ushort_t* gB[2];
    ushort_t* lB[2];
#pragma unroll
    for (int t = 0; t < 2; ++t) {
        int s = tid + t * 256;
        int r = s >> 3, gl = (s & 7) ^ (r & 7);
        gB[t] = W + (size_t)(bn + r) * K + gl * 8;
        lB[t] = &Bs[s * 8];
    }

    const int fr = lane & 15;
    const int fq = lane >> 4;
    int aoff[4][2], boff[2][2];
#pragma unroll
    for (int t = 0; t < 4; ++t)
#pragma unroll
        for (int s = 0; s < 2; ++s)
            aoff[t][s] = LSLOT64(wm + t * 16 + fr, s * 4 + fq);
#pragma unroll
    for (int t = 0; t < 2; ++t)
#pragma unroll
        for (int s = 0; s < 2; ++s)
            boff[t][s] = LSLOT64(wn + t * 16 + fr, s * 4 + fq);

    f32x4 acc[4][2];
#pragma unroll
    for (int i = 0; i < 4; ++i)
#pragma unroll
        for (int j = 0; j < 2; ++j) acc[i][j] = (f32x4){0.f, 0.f, 0.f, 0.f};

    for (int k0 = 0; k0 < K; k0 += 64) {
#pragma unroll
        for (int t = 0; t < 4; ++t) gload_lds16(gA[t] + k0, lA[t]);
#pragma unroll
        for (int t = 0; t < 2; ++t) gload_lds16(gB[t] + k0, lB[t]);
        __syncthreads();

#pragma unroll
        for (int s = 0; s < 2; ++s) {
            bf16x8 af[4], bf[2];
#pragma unroll
            for (int t = 0; t < 4; ++t) af[t] = *(const bf16x8*)&As[aoff[t][s]];
#pragma unroll
            for (int t = 0; t < 2; ++t) bf[t] = *(const bf16x8*)&Bs[boff[t][s]];
#pragma unroll
            for (int i = 0; i < 4; ++i)
#pragma unroll
                for (int j = 0; j < 2; ++j)
                    acc[i][j] = __builtin_amdgcn_mfma_f32_16x16x32_bf16(
                        af[i], bf[j], acc[i][j], 0, 0, 0);
        }
        __syncthreads();
    }

#pragma unroll
    for (int tj = 0; tj < 2; ++tj) {
        const int n = bn + wn + tj * 16 + fr;
        const float bv = bias[n];
#pragma unroll
        for (int ti = 0; ti < 4; ++ti) {
            const int m0 = bm + wm + ti * 16 + fq * 4;
            f32x4 a = acc[ti][tj];
#pragma unroll
            for (int r = 0; r < 4; ++r) {
                float v = a[r] + bv;
                if (do_gelu) v = gelu_exact(v);
                const size_t off = (size_t)(m0 + r) * N + n;
                if (Cf) Cf[off] = v;
                if (Cb) Cb[off] = f2bf(v);
            }
        }
    }
}

// ---------------- QKV GEMM: 256x256 tile, BK=64, 8-phase counted-vmcnt -----
// 192 blocks x 512 threads; 8 waves as 2(M)x4(N); per-wave 128x64 strided:
// wave (wm,wn) owns rows {mh*128 + wm*64 + [0,64)} x cols {nh*128 + wn*32 + [0,32)}
// so phase (mh,nh) reads exactly A-staging-half mh and B-staging-half nh.
// Staging order per K-tile t (for t+1): Ah0@q0, Bh0@q1, Bh1@q2, Ah1@q3
// (2 loads each) => every read's half is >=3 phases old under vmcnt(4).
#define QPHASE(par, mh, nh, LOADA, ...)                                        \
    {                                                                          \
        if (LOADA) {                                                           \
            _Pragma("unroll") for (int im = 0; im < 4; ++im)                   \
                _Pragma("unroll") for (int ks = 0; ks < 2; ++ks)               \
                    af[im][ks] = *(const bf16x8*)&AsB[(par)*16384 +            \
                                                     (mh)*8192 + aoff[im][ks]];\
        }                                                                      \
        _Pragma("unroll") for (int jn = 0; jn < 2; ++jn)                       \
            _Pragma("unroll") for (int ks = 0; ks < 2; ++ks)                   \
                bfv[jn][ks] = *(const bf16x8*)&BsB[(par)*16384 +               \
                                                  (nh)*8192 + boff[jn][ks]];   \
        __VA_ARGS__;                                                           \
        __builtin_amdgcn_s_barrier();                                          \
        asm volatile("s_waitcnt lgkmcnt(0)" ::: "memory");                     \
        __builtin_amdgcn_sched_barrier(0);                                     \
        __builtin_amdgcn_s_setprio(1);                                         \
        _Pragma("unroll") for (int im = 0; im < 4; ++im)                       \
            _Pragma("unroll") for (int jn = 0; jn < 2; ++jn)                   \
                _Pragma("unroll") for (int ks = 0; ks < 2; ++ks)               \
                    acc[(mh)*4 + im][(nh)*2 + jn] =                            \
                        __builtin_amdgcn_mfma_f32_16x16x32_bf16(               \
                            af[im][ks], bfv[jn][ks],                           \
                            acc[(mh)*4 + im][(nh)*2 + jn], 0, 0, 0);           \
        __builtin_amdgcn_s_setprio(0);                                         \
        asm volatile("s_waitcnt vmcnt(4)" ::: "memory");                       \
        __builtin_amdgcn_s_barrier();                                          \
    }

__global__ __launch_bounds__(512, 2) void gemm_qkv256(
    const ushort_t* __restrict__ A, const ushort_t* __restrict__ W,
    const float* __restrict__ bias, ushort_t* __restrict__ Qb,
    ushort_t* __restrict__ Kb, ushort_t* __restrict__ Vt) {
    extern __shared__ ushort_t lds[];
    ushort_t* AsB = lds;           // [2][256*64] = 64 KB
    ushort_t* BsB = lds + 32768;   // [2][256*64] = 64 KB
    const int K = 1024;

    // XCD-bijective swizzle: 192 blocks = 8 XCDs x 24
    const int bid = blockIdx.x;
    const int wg = (bid & 7) * 24 + (bid >> 3);
    const int by = wg / 12, bx = wg - by * 12;
    const int bm = by * 256, bn = bx * 256;

    const int tid = threadIdx.x;
    const int lane = tid & 63;
    const int w = tid >> 6;    // 0..7
    const int wm = w >> 2;     // 0..1
    const int wn = w & 3;      // 0..3
    const int fr = lane & 15;
    const int fq = lane >> 4;

    // staging: half = 128 rows x 8 chunks = 1024 slots; 512 thr -> 2 loads
    const ushort_t* gA[2];
    const ushort_t* gB[2];
    int sdst[2];
#pragma unroll
    for (int u = 0; u < 2; ++u) {
        int s = tid + u * 512;
        int r = s >> 3, c = (s & 7) ^ (r & 7);
        gA[u] = A + (size_t)(bm + r) * K + c * 8;
        gB[u] = W + (size_t)(bn + r) * K + c * 8;
        sdst[u] = s * 8;
    }

    int aoff[4][2], boff[2][2];
#pragma unroll
    for (int im = 0; im < 4; ++im)
#pragma unroll
        for (int ks = 0; ks < 2; ++ks)
            aoff[im][ks] = LSLOT64(wm * 64 + im * 16 + fr, ks * 4 + fq);
#pragma unroll
    for (int jn = 0; jn < 2; ++jn)
#pragma unroll
        for (int ks = 0; ks < 2; ++ks)
            boff[jn][ks] = LSLOT64(wn * 32 + jn * 16 + fr, ks * 4 + fq);

    f32x4 acc[8][4];
#pragma unroll
    for (int i = 0; i < 8; ++i)
#pragma unroll
        for (int j = 0; j < 4; ++j) acc[i][j] = (f32x4){0.f, 0.f, 0.f, 0.f};

    auto stageA = [&](int p, int h, int tk) {
#pragma unroll
        for (int u = 0; u < 2; ++u)
            gload_lds16(gA[u] + (size_t)h * 128 * K + tk * 64,
                        &AsB[p * 16384 + h * 8192 + sdst[u]]);
    };
    auto stageB = [&](int p, int h, int tk) {
#pragma unroll
        for (int u = 0; u < 2; ++u)
            gload_lds16(gB[u] + (size_t)h * 128 * K + tk * 64,
                        &BsB[p * 16384 + h * 8192 + sdst[u]]);
    };

    // prologue: tile 0 -> buf 0, full drain once
    stageA(0, 0, 0); stageB(0, 0, 0); stageB(0, 1, 0); stageA(0, 1, 0);
    asm volatile("s_waitcnt vmcnt(0)" ::: "memory");
    __builtin_amdgcn_s_barrier();

    bf16x8 af[4][2], bfv[2][2];

#pragma unroll 1
    for (int it = 0; it < 8; ++it) {
        const int t0 = 2 * it;
        // tile t0 (buf 0): stage tile t0+1 -> buf 1
        QPHASE(0, 0, 0, 1, { stageA(1, 0, t0 + 1); })
        QPHASE(0, 0, 1, 0, { stageB(1, 0, t0 + 1); })
        QPHASE(0, 1, 0, 1, { stageB(1, 1, t0 + 1); })
        QPHASE(0, 1, 1, 0, { stageA(1, 1, t0 + 1); })
        // tile t0+1 (buf 1): stage tile t0+2 -> buf 0 (guard last)
        const bool st = (it < 7);
        QPHASE(1, 0, 0, 1, { if (st) stageA(0, 0, t0 + 2); })
        QPHASE(1, 0, 1, 0, { if (st) stageB(0, 0, t0 + 2); })
        QPHASE(1, 1, 0, 1, { if (st) stageB(0, 1, t0 + 2); })
        QPHASE(1, 1, 1, 0, { if (st) stageA(0, 1, t0 + 2); })
    }

    const float qscale = 0.08838834764831845f;
#pragma unroll
    for (int j = 0; j < 4; ++j) {
        const int n = bn + (j >> 1) * 128 + wn * 32 + (j & 1) * 16 + fr;
        const float bv = bias[n];
#pragma unroll
        for (int i = 0; i < 8; ++i) {
            const int m0 = bm + (i >> 2) * 128 + wm * 64 + (i & 3) * 16 + fq * 4;
            f32x4 a = acc[i][j];
            if (n < D) {
#pragma unroll
                for (int r = 0; r < 4; ++r)
                    Qb[(size_t)(m0 + r) * D + n] = f2bf((a[r] + bv) * qscale);
            } else if (n < 2 * D) {
#pragma unroll
                for (int r = 0; r < 4; ++r)
                    Kb[(size_t)(m0 + r) * D + (n - D)] = f2bf(a[r] + bv);
            } else {
                const int h = (n - 2 * D) >> 7;
                const int dh = (n - 2 * D) & 127;
                const int bb = m0 >> 9;
                const int t = m0 & 511;
                ushort4 pk;
                pk.x = f2bf(a[0] + bv); pk.y = f2bf(a[1] + bv);
                pk.z = f2bf(a[2] + bv); pk.w = f2bf(a[3] + bv);
                *(ushort4*)&Vt[((size_t)(bb * H + h) * DH + dh) * TL + t] = pk;
            }
        }
    }
}

// ---------------- MFMA flash attention -------------------------------------
#define LSW16(r, g) ((((r) << 4) + ((g) ^ ((r) & 7))) << 3)
#define LSW8(r, g) ((((r) << 3) + ((g) ^ ((r) & 7))) << 3)

__global__ __launch_bounds__(256, 2) void attn_mfma(
    const ushort_t* __restrict__ Qb, const ushort_t* __restrict__ Kb,
    const ushort_t* __restrict__ Vt, ushort_t* __restrict__ Ab) {
    __shared__ ushort_t Qs[64 * 128];
    __shared__ ushort_t Ks[64 * 128];
    __shared__ ushort_t Vts[128 * 64];
    __shared__ ushort_t Ps[64 * 72];

    const int q0 = blockIdx.x * 64;
    const int bh = blockIdx.y;
    const int b = bh >> 3;
    const int h = bh & 7;
    const int tid = threadIdx.x;
    const int lane = tid & 63;
    const int w = tid >> 6;
    const int fr = lane & 15;
    const int fq = lane >> 4;

    const float slope = exp2f(-(float)(h + 1));

#pragma unroll
    for (int kk = 0; kk < 4; ++kk) {
        int s = tid + kk * 256;
        int r = s >> 4, gp = s & 15, gl = gp ^ (r & 7);
        gload_lds16(Qb + (size_t)(b * TL + q0 + r) * D + h * DH + gl * 8,
                    &Qs[s * 8]);
    }

    f32x4 o8[8];
    float m_i[4], l_i[4];
#pragma unroll
    for (int nt = 0; nt < 8; ++nt) o8[nt] = (f32x4){0.f, 0.f, 0.f, 0.f};
#pragma unroll
    for (int r = 0; r < 4; ++r) { m_i[r] = -1e30f; l_i[r] = 0.f; }

    for (int kt = 0; kt < TL / 64; ++kt) {
        __syncthreads();
#pragma unroll
        for (int kk = 0; kk < 4; ++kk) {
            int s = tid + kk * 256;
            int r = s >> 4, gp = s & 15, gl = gp ^ (r & 7);
            gload_lds16(Kb + (size_t)(b * TL + kt * 64 + r) * D + h * DH + gl * 8,
                        &Ks[s * 8]);
        }
#pragma unroll
        for (int kk = 0; kk < 4; ++kk) {
            int s = tid + kk * 256;
            int r = s >> 3, gp = s & 7, gl = gp ^ (r & 7);
            gload_lds16(Vt + ((size_t)bh * DH + r) * TL + kt * 64 + gl * 8,
                        &Vts[s * 8]);
        }
        __syncthreads();

        f32x4 sacc[4];
#pragma unroll
        for (int jt = 0; jt < 4; ++jt) sacc[jt] = (f32x4){0.f, 0.f, 0.f, 0.f};
#pragma unroll
        for (int s4 = 0; s4 < 4; ++s4) {
            bf16x8 aq = *(const bf16x8*)&Qs[LSW16(w * 16 + fr, s4 * 4 + fq)];
#pragma unroll
            for (int jt = 0; jt < 4; ++jt) {
                bf16x8 kb = *(const bf16x8*)&Ks[LSW16(jt * 16 + fr, s4 * 4 + fq)];
                sacc[jt] = __builtin_amdgcn_mfma_f32_16x16x32_bf16(
                    aq, kb, sacc[jt], 0, 0, 0);
            }
        }

        const int iq = q0 + w * 16 + fq * 4;
        const int jk = kt * 64 + fr;
        float al[4];
#pragma unroll
        for (int r = 0; r < 4; ++r) {
            float sv[4];
#pragma unroll
            for (int jt = 0; jt < 4; ++jt)
                sv[jt] = sacc[jt][r] -
                         slope * fabsf((float)(iq + r - jk - jt * 16));
            float mx = fmaxf(fmaxf(sv[0], sv[1]), fmaxf(sv[2], sv[3]));
            mx = fmaxf(mx, __shfl_xor(mx, 1));
            mx = fmaxf(mx, __shfl_xor(mx, 2));
            mx = fmaxf(mx, __shfl_xor(mx, 4));
            mx = fmaxf(mx, __shfl_xor(mx, 8));
            float mnew = fmaxf(m_i[r], mx);
            al[r] = __expf(m_i[r] - mnew);
            float rs = 0.f;
#pragma unroll
            for (int jt = 0; jt < 4; ++jt) {
                sv[jt] = __expf(sv[jt] - mnew);
                rs += sv[jt];
            }
            rs += __shfl_xor(rs, 1);
            rs += __shfl_xor(rs, 2);
            rs += __shfl_xor(rs, 4);
            rs += __shfl_xor(rs, 8);
            l_i[r] = l_i[r] * al[r] + rs;
            m_i[r] = mnew;
            const int prow = w * 16 + fq * 4 + r;
#pragma unroll
            for (int jt = 0; jt < 4; ++jt)
                Ps[prow * 72 + jt * 16 + fr] = f2bf(sv[jt]);
        }
#pragma unroll
        for (int nt = 0; nt < 8; ++nt)
#pragma unroll
            for (int r = 0; r < 4; ++r) o8[nt][r] *= al[r];

#pragma unroll
        for (int s2 = 0; s2 < 2; ++s2) {
            bf16x8 pa = *(const bf16x8*)&Ps[(w * 16 + fr) * 72 + s2 * 32 + fq * 8];
#pragma unroll
            for (int nt = 0; nt < 8; ++nt) {
                bf16x8 vb = *(const bf16x8*)&Vts[LSW8(nt * 16 + fr, s2 * 4 + fq)];
                o8[nt] = __builtin_amdgcn_mfma_f32_16x16x32_bf16(
                    pa, vb, o8[nt], 0, 0, 0);
            }
        }
    }

#pragma unroll
    for (int r = 0; r < 4; ++r) {
        float inv = 1.f / l_i[r];
        const size_t base = (size_t)(b * TL + q0 + w * 16 + fq * 4 + r) * D + h * DH;
#pragma unroll
        for (int nt = 0; nt < 8; ++nt)
            Ab[base + nt * 16 + fr] = f2bf(o8[nt][r] * inv);
    }
}

// ---------------- fused residual + LayerNorm, one wave per row -------------
__global__ __launch_bounds__(256) void add_ln(const float* __restrict__ x,
                                              const float* __restrict__ y,
                                              const float* __restrict__ g,
                                              const float* __restrict__ bta,
                                              float* __restrict__ out,
                                              ushort_t* __restrict__ outb) {
    const int row = blockIdx.x * 4 + (threadIdx.x >> 6);
    const int lane = threadIdx.x & 63;
    const size_t rbase = (size_t)row * D;

    float4 v[4];
#pragma unroll
    for (int j = 0; j < 4; ++j) {
        float4 xv = *(const float4*)(x + rbase + lane * 4 + j * 256);
        float4 yv = *(const float4*)(y + rbase + lane * 4 + j * 256);
        v[j].x = xv.x + yv.x; v[j].y = xv.y + yv.y;
        v[j].z = xv.z + yv.z; v[j].w = xv.w + yv.w;
    }

    float s = 0.f;
#pragma unroll
    for (int j = 0; j < 4; ++j) s += v[j].x + v[j].y + v[j].z + v[j].w;
#pragma unroll
    for (int off = 32; off; off >>= 1) s += __shfl_xor(s, off);
    const float mean = s * (1.f / (float)D);

    float sq = 0.f;
#pragma unroll
    for (int j = 0; j < 4; ++j) {
        float d0 = v[j].x - mean, d1 = v[j].y - mean;
        float d2 = v[j].z - mean, d3 = v[j].w - mean;
        sq += d0 * d0 + d1 * d1 + d2 * d2 + d3 * d3;
    }
#pragma unroll
    for (int off = 32; off; off >>= 1) sq += __shfl_xor(sq, off);
    const float var = sq * (1.f / (float)D);
    const float inv = rsqrtf(var + 1e-5f);

#pragma unroll
    for (int j = 0; j < 4; ++j) {
        const int col = lane * 4 + j * 256;
        float4 gv = *(const float4*)(g + col);
        float4 bv = *(const float4*)(bta + col);
        float4 o;
        o.x = (v[j].x - mean) * inv * gv.x + bv.x;
        o.y = (v[j].y - mean) * inv * gv.y + bv.y;
        o.z = (v[j].z - mean) * inv * gv.z + bv.z;
        o.w = (v[j].w - mean) * inv * gv.w + bv.w;
        *(float4*)(out + rbase + col) = o;
        ushort4 ob;
        ob.x = f2bf(o.x); ob.y = f2bf(o.y); ob.z = f2bf(o.z); ob.w = f2bf(o.w);
        *(ushort4*)(outb + rbase + col) = ob;
    }
}

// ---------------- launcher -------------------------------------------------
extern "C" void kernel_launch(void* const* d_in, const int* in_sizes, int n_in,
                              void* d_out, int out_size, void* d_ws, size_t ws_size,
                              hipStream_t stream) {
    const float* x_in   = (const float*)d_in[0];
    const float* pre_w  = (const float*)d_in[1];
    const float* pre_b  = (const float*)d_in[2];
    const float* in_w   = (const float*)d_in[3];
    const float* in_b   = (const float*)d_in[4];
    const float* out_w  = (const float*)d_in[5];
    const float* out_b  = (const float*)d_in[6];
    const float* ln1_g  = (const float*)d_in[7];
    const float* ln1_b  = (const float*)d_in[8];
    const float* ff1_w  = (const float*)d_in[9];
    const float* ff1_b  = (const float*)d_in[10];
    const float* ff2_w  = (const float*)d_in[11];
    const float* ff2_b  = (const float*)d_in[12];
    const float* ln2_g  = (const float*)d_in[13];
    const float* ln2_b  = (const float*)d_in[14];
    const float* post_w = (const float*)d_in[15];
    const float* post_b = (const float*)d_in[16];

    static bool attr_set = false;
    if (!attr_set) {
        hipFuncSetAttribute((const void*)gemm_qkv256,
                            hipFuncAttributeMaxDynamicSharedMemorySize, 131072);
        attr_set = true;
    }

    float* X = (float*)d_ws;
    float* Y = X + (size_t)M_ROWS * D;
    ushort_t* Xb   = (ushort_t*)(Y + (size_t)M_ROWS * D);
    ushort_t* Ab   = Xb + (size_t)M_ROWS * D;
    ushort_t* Qb   = Ab + (size_t)M_ROWS * D;
    ushort_t* Kb   = Qb + (size_t)M_ROWS * D;
    ushort_t* Vt   = Kb + (size_t)M_ROWS * D;
    ushort_t* xinb = Vt + (size_t)M_ROWS * D;
    ushort_t* pwb  = xinb + (size_t)M_ROWS * 512;
    ushort_t* iwb  = pwb + (size_t)D * 512;
    ushort_t* owb  = iwb + (size_t)NL * 3 * D * D;
    ushort_t* f1wb = owb + (size_t)NL * D * D;
    ushort_t* f2wb = f1wb + (size_t)NL * DFF * D;
    ushort_t* powb = f2wb + (size_t)NL * D * DFF;

    const dim3 blk(256);

    CvtArgs ca;
    ca.s[0] = x_in;   ca.d[0] = xinb; ca.nq[0] = (M_ROWS * 512) / 4;
    ca.s[1] = pre_w;  ca.d[1] = pwb;  ca.nq[1] = (D * 512) / 4;
    ca.s[2] = in_w;   ca.d[2] = iwb;  ca.nq[2] = (NL * 3 * D * D) / 4;
    ca.s[3] = out_w;  ca.d[3] = owb;  ca.nq[3] = (NL * D * D) / 4;
    ca.s[4] = ff1_w;  ca.d[4] = f1wb; ca.nq[4] = (NL * DFF * D) / 4;
    ca.s[5] = ff2_w;  ca.d[5] = f2wb; ca.nq[5] = (NL * D * DFF) / 4;
    ca.s[6] = post_w; ca.d[6] = powb; ca.nq[6] = (D * D) / 4;
    {
        long long total = 0;
        for (int i = 0; i < 7; ++i) total += ca.nq[i];
        long long cum = 0;
        ca.bstart[0] = 0;
        for (int i = 0; i < 7; ++i) {
            cum += ca.nq[i];
            ca.bstart[i + 1] = (int)((cum * 4096) / total);
        }
        ca.bstart[7] = 4096;
    }
    cvt_all<<<4096, blk, 0, stream>>>(ca);

    const dim3 gN64(D / 64, M_ROWS / 128);          // 512 blocks

    gemm_n64<<<gN64, blk, 0, stream>>>(xinb, pwb, pre_b, X, Xb,
                                       M_ROWS, D, 512, 0);

    for (int l = 0; l < NL; ++l) {
        gemm_qkv256<<<dim3(192), dim3(512), 131072, stream>>>(
            Xb, iwb + (size_t)l * 3 * D * D, in_b + (size_t)l * 3 * D,
            Qb, Kb, Vt);
        attn_mfma<<<dim3(TL / 64, B * H), blk, 0, stream>>>(Qb, Kb, Vt, Ab);
        gemm_n64<<<gN64, blk, 0, stream>>>(Ab, owb + (size_t)l * D * D,
                                           out_b + (size_t)l * D, Y, nullptr,
                                           M_ROWS, D, D, 0);
        add_ln<<<dim3(M_ROWS / 4), blk, 0, stream>>>(X, Y, ln1_g + (size_t)l * D,
                                                     ln1_b + (size_t)l * D, X, Xb);
        gemm_n64<<<gN64, blk, 0, stream>>>(Xb, f1wb + (size_t)l * DFF * D,
                                           ff1_b + (size_t)l * DFF, nullptr, Ab,
                                           M_ROWS, DFF, D, 1);
        gemm_n64<<<gN64, blk, 0, stream>>>(Ab, f2wb + (size_t)l * D * DFF,
                                           ff2_b + (size_t)l * D, Y, nullptr,
                                           M_ROWS, D, DFF, 0);
        add_ln<<<dim3(M_ROWS / 4), blk, 0, stream>>>(X, Y, ln2_g + (size_t)l * D,
                                                     ln2_b + (size_t)l * D, X, Xb);
    }

    gemm_n64<<<gN64, blk, 0, stream>>>(Xb, powb, post_b, (float*)d_out, nullptr,
                                       M_ROWS, D, D, 0);
}

// Round 4
// 1126.805 us; speedup vs baseline: 1.1439x; 1.0041x over previous
//
#include <hip/hip_runtime.h>
#include <hip/hip_bf16.h>

// ---------------- problem constants ----------------
#define B 8
#define TL 512
#define M_ROWS 4096
#define D 1024
#define DFF 1024
#define H 8
#define DH 128
#define NL 6

typedef unsigned short ushort_t;
typedef unsigned int uint_t;
typedef short bf16x8 __attribute__((ext_vector_type(8)));
typedef float f32x4 __attribute__((ext_vector_type(4)));

__device__ __forceinline__ ushort_t f2bf(float f) {
    uint_t u = __float_as_uint(f);
    u += 0x7FFFu + ((u >> 16) & 1u);
    return (ushort_t)(u >> 16);
}
__device__ __forceinline__ float gelu_exact(float x) {
    return 0.5f * x * (1.0f + erff(x * 0.70710678118654752f));
}
__device__ __forceinline__ void gload_lds16(const ushort_t* g, ushort_t* l) {
    __builtin_amdgcn_global_load_lds(
        (const __attribute__((address_space(1))) void*)g,
        (__attribute__((address_space(3))) void*)l, 16, 0, 0);
}

// ---------------- f32 -> bf16 conversion, block-partitioned ----------------
struct CvtArgs {
    const float* s[7];
    ushort_t* d[7];
    int nq[7];      // float4-chunk counts
    int bstart[8];  // block ranges per segment
};

__global__ __launch_bounds__(256) void cvt_all(CvtArgs a) {
    const int bid = blockIdx.x;
#pragma unroll
    for (int seg = 0; seg < 7; ++seg) {
        const int b0 = a.bstart[seg], b1 = a.bstart[seg + 1];
        if (bid < b0 || bid >= b1) continue;
        const int stride = (b1 - b0) * 256;
        const float* s = a.s[seg];
        ushort_t* d = a.d[seg];
        const int nq = a.nq[seg];
        for (int i = (bid - b0) * 256 + threadIdx.x; i < nq; i += stride) {
            float4 v = *(const float4*)(s + (size_t)i * 4);
            ushort4 o;
            o.x = f2bf(v.x); o.y = f2bf(v.y); o.z = f2bf(v.z); o.w = f2bf(v.w);
            *(ushort4*)(d + (size_t)i * 4) = o;
        }
    }
}

// LDS row = 8 chunks of 16B (BK=64 bf16); XOR swizzle baked into staging.
#define LSLOT64(r, c) (((r) * 8 + ((c) ^ ((r) & 7))) * 8)

// ---------------- N GEMM: 128x128 tile, BK=64, 2-phase stage-early dbuf ----
// 512 threads = 8 waves (2M x 4N); per-wave 64x32 out = acc[4][2].
// LDS (dynamic 64 KB): A bufs [0,16K)+[16K,32K) ushorts? -- layout below:
//   A[buf] = lds + buf*8192, B[buf] = lds + 16384 + buf*8192  (ushort idx)
// Epilogue: LDS-transpose ([64][132] f32) -> float4/ushort4 wide stores.
__global__ __launch_bounds__(512) void gemm_n128(
    const ushort_t* __restrict__ A, const ushort_t* __restrict__ W,
    const float* __restrict__ bias, float* __restrict__ Cf,
    ushort_t* __restrict__ Cb, int M, int N, int K, int do_gelu) {
    extern __shared__ ushort_t lds[];

    const int tid = threadIdx.x;
    const int lane = tid & 63;
    const int w = tid >> 6;    // 0..7
    const int wm = w >> 2;     // 0..1 -> 64-row half
    const int wn = w & 3;      // 0..3 -> 32-col strip
    const int bm = blockIdx.y * 128;
    const int bn = blockIdx.x * 128;
    const int fr = lane & 15;
    const int fq = lane >> 4;

    // staging: tile = 128 rows x 8 chunks = 1024 slots; 512 thr -> 2 each
    const ushort_t* gA[2];
    const ushort_t* gB[2];
    int sdst[2];
#pragma unroll
    for (int u = 0; u < 2; ++u) {
        int s = tid + u * 512;
        int r = s >> 3, c = (s & 7) ^ (r & 7);
        gA[u] = A + (size_t)(bm + r) * K + c * 8;
        gB[u] = W + (size_t)(bn + r) * K + c * 8;
        sdst[u] = s * 8;
    }

    int aoff[4][2], boff[2][2];
#pragma unroll
    for (int ti = 0; ti < 4; ++ti)
#pragma unroll
        for (int ks = 0; ks < 2; ++ks)
            aoff[ti][ks] = LSLOT64(wm * 64 + ti * 16 + fr, ks * 4 + fq);
#pragma unroll
    for (int tj = 0; tj < 2; ++tj)
#pragma unroll
        for (int ks = 0; ks < 2; ++ks)
            boff[tj][ks] = LSLOT64(wn * 32 + tj * 16 + fr, ks * 4 + fq);

    f32x4 acc[4][2];
#pragma unroll
    for (int i = 0; i < 4; ++i)
#pragma unroll
        for (int j = 0; j < 2; ++j) acc[i][j] = (f32x4){0.f, 0.f, 0.f, 0.f};

    auto stage = [&](int buf, int k0) {
#pragma unroll
        for (int u = 0; u < 2; ++u)
            gload_lds16(gA[u] + k0, &lds[buf * 8192 + sdst[u]]);
#pragma unroll
        for (int u = 0; u < 2; ++u)
            gload_lds16(gB[u] + k0, &lds[16384 + buf * 8192 + sdst[u]]);
    };
    auto comp = [&](int buf) {
#pragma unroll
        for (int ks = 0; ks < 2; ++ks) {
            bf16x8 af[4], bfv[2];
#pragma unroll
            for (int ti = 0; ti < 4; ++ti)
                af[ti] = *(const bf16x8*)&lds[buf * 8192 + aoff[ti][ks]];
#pragma unroll
            for (int tj = 0; tj < 2; ++tj)
                bfv[tj] = *(const bf16x8*)&lds[16384 + buf * 8192 + boff[tj][ks]];
#pragma unroll
            for (int i = 0; i < 4; ++i)
#pragma unroll
                for (int j = 0; j < 2; ++j)
                    acc[i][j] = __builtin_amdgcn_mfma_f32_16x16x32_bf16(
                        af[i], bfv[j], acc[i][j], 0, 0, 0);
        }
    };

    const int NT = K >> 6;
    stage(0, 0);
    __syncthreads();
    int buf = 0;
    for (int t = 0; t < NT; ++t) {
        if (t + 1 < NT) stage(buf ^ 1, (t + 1) * 64);  // issue BEFORE compute
        comp(buf);
        __syncthreads();  // single drain+barrier per K-tile
        buf ^= 1;
    }

    // ---- epilogue: LDS transpose to wide stores ----
    float bv[2];
#pragma unroll
    for (int tj = 0; tj < 2; ++tj) bv[tj] = bias[bn + wn * 32 + tj * 16 + fr];

    float* eps = (float*)lds;  // [64][132] f32 = 33.8 KB
#pragma unroll
    for (int p = 0; p < 2; ++p) {
        if (p) __syncthreads();
        if (wm == p) {
#pragma unroll
            for (int ti = 0; ti < 4; ++ti)
#pragma unroll
                for (int tj = 0; tj < 2; ++tj)
#pragma unroll
                    for (int r = 0; r < 4; ++r) {
                        float v = acc[ti][tj][r] + bv[tj];
                        if (do_gelu) v = gelu_exact(v);
                        eps[(ti * 16 + fq * 4 + r) * 132 +
                            wn * 32 + tj * 16 + fr] = v;
                    }
        }
        __syncthreads();
#pragma unroll
        for (int k = 0; k < 4; ++k) {
            int f = tid + k * 512;        // 0..2047
            int row = f >> 5, c4 = f & 31;
            float4 v = *(const float4*)&eps[row * 132 + c4 * 4];
            const size_t off = (size_t)(bm + p * 64 + row) * N + bn + c4 * 4;
            if (Cf) *(float4*)(Cf + off) = v;
            if (Cb) {
                ushort4 ob;
                ob.x = f2bf(v.x); ob.y = f2bf(v.y);
                ob.z = f2bf(v.z); ob.w = f2bf(v.w);
                *(ushort4*)(Cb + off) = ob;
            }
        }
    }
}

// ---------------- QKV GEMM: 256x256 tile, BK=64, 8-phase counted-vmcnt -----
#define QPHASE(par, mh, nh, LOADA, ...)                                        \
    {                                                                          \
        if (LOADA) {                                                           \
            _Pragma("unroll") for (int im = 0; im < 4; ++im)                   \
                _Pragma("unroll") for (int ks = 0; ks < 2; ++ks)               \
                    af[im][ks] = *(const bf16x8*)&AsB[(par)*16384 +            \
                                                     (mh)*8192 + aoff[im][ks]];\
        }                                                                      \
        _Pragma("unroll") for (int jn = 0; jn < 2; ++jn)                       \
            _Pragma("unroll") for (int ks = 0; ks < 2; ++ks)                   \
                bfv[jn][ks] = *(const bf16x8*)&BsB[(par)*16384 +               \
                                                  (nh)*8192 + boff[jn][ks]];   \
        __VA_ARGS__;                                                           \
        __builtin_amdgcn_s_barrier();                                          \
        asm volatile("s_waitcnt lgkmcnt(0)" ::: "memory");                     \
        __builtin_amdgcn_sched_barrier(0);                                     \
        __builtin_amdgcn_s_setprio(1);                                         \
        _Pragma("unroll") for (int im = 0; im < 4; ++im)                       \
            _Pragma("unroll") for (int jn = 0; jn < 2; ++jn)                   \
                _Pragma("unroll") for (int ks = 0; ks < 2; ++ks)               \
                    acc[(mh)*4 + im][(nh)*2 + jn] =                            \
                        __builtin_amdgcn_mfma_f32_16x16x32_bf16(               \
                            af[im][ks], bfv[jn][ks],                           \
                            acc[(mh)*4 + im][(nh)*2 + jn], 0, 0, 0);           \
        __builtin_amdgcn_s_setprio(0);                                         \
        asm volatile("s_waitcnt vmcnt(4)" ::: "memory");                       \
        __builtin_amdgcn_s_barrier();                                          \
    }

__global__ __launch_bounds__(512, 2) void gemm_qkv256(
    const ushort_t* __restrict__ A, const ushort_t* __restrict__ W,
    const float* __restrict__ bias, ushort_t* __restrict__ Qb,
    ushort_t* __restrict__ Kb, ushort_t* __restrict__ Vt) {
    extern __shared__ ushort_t lds[];
    ushort_t* AsB = lds;           // [2][256*64] = 64 KB
    ushort_t* BsB = lds + 32768;   // [2][256*64] = 64 KB
    const int K = 1024;

    // XCD-bijective swizzle: 192 blocks = 8 XCDs x 24
    const int bid = blockIdx.x;
    const int wg = (bid & 7) * 24 + (bid >> 3);
    const int by = wg / 12, bx = wg - by * 12;
    const int bm = by * 256, bn = bx * 256;

    const int tid = threadIdx.x;
    const int lane = tid & 63;
    const int w = tid >> 6;    // 0..7
    const int wm = w >> 2;     // 0..1
    const int wn = w & 3;      // 0..3
    const int fr = lane & 15;
    const int fq = lane >> 4;

    const ushort_t* gA[2];
    const ushort_t* gB[2];
    int sdst[2];
#pragma unroll
    for (int u = 0; u < 2; ++u) {
        int s = tid + u * 512;
        int r = s >> 3, c = (s & 7) ^ (r & 7);
        gA[u] = A + (size_t)(bm + r) * K + c * 8;
        gB[u] = W + (size_t)(bn + r) * K + c * 8;
        sdst[u] = s * 8;
    }

    int aoff[4][2], boff[2][2];
#pragma unroll
    for (int im = 0; im < 4; ++im)
#pragma unroll
        for (int ks = 0; ks < 2; ++ks)
            aoff[im][ks] = LSLOT64(wm * 64 + im * 16 + fr, ks * 4 + fq);
#pragma unroll
    for (int jn = 0; jn < 2; ++jn)
#pragma unroll
        for (int ks = 0; ks < 2; ++ks)
            boff[jn][ks] = LSLOT64(wn * 32 + jn * 16 + fr, ks * 4 + fq);

    f32x4 acc[8][4];
#pragma unroll
    for (int i = 0; i < 8; ++i)
#pragma unroll
        for (int j = 0; j < 4; ++j) acc[i][j] = (f32x4){0.f, 0.f, 0.f, 0.f};

    auto stageA = [&](int p, int h, int tk) {
#pragma unroll
        for (int u = 0; u < 2; ++u)
            gload_lds16(gA[u] + (size_t)h * 128 * K + tk * 64,
                        &AsB[p * 16384 + h * 8192 + sdst[u]]);
    };
    auto stageB = [&](int p, int h, int tk) {
#pragma unroll
        for (int u = 0; u < 2; ++u)
            gload_lds16(gB[u] + (size_t)h * 128 * K + tk * 64,
                        &BsB[p * 16384 + h * 8192 + sdst[u]]);
    };

    stageA(0, 0, 0); stageB(0, 0, 0); stageB(0, 1, 0); stageA(0, 1, 0);
    asm volatile("s_waitcnt vmcnt(0)" ::: "memory");
    __builtin_amdgcn_s_barrier();

    bf16x8 af[4][2], bfv[2][2];

#pragma unroll 1
    for (int it = 0; it < 8; ++it) {
        const int t0 = 2 * it;
        QPHASE(0, 0, 0, 1, { stageA(1, 0, t0 + 1); })
        QPHASE(0, 0, 1, 0, { stageB(1, 0, t0 + 1); })
        QPHASE(0, 1, 0, 1, { stageB(1, 1, t0 + 1); })
        QPHASE(0, 1, 1, 0, { stageA(1, 1, t0 + 1); })
        const bool st = (it < 7);
        QPHASE(1, 0, 0, 1, { if (st) stageA(0, 0, t0 + 2); })
        QPHASE(1, 0, 1, 0, { if (st) stageB(0, 0, t0 + 2); })
        QPHASE(1, 1, 0, 1, { if (st) stageB(0, 1, t0 + 2); })
        QPHASE(1, 1, 1, 0, { if (st) stageA(0, 1, t0 + 2); })
    }

    const float qscale = 0.08838834764831845f;
#pragma unroll
    for (int j = 0; j < 4; ++j) {
        const int n = bn + (j >> 1) * 128 + wn * 32 + (j & 1) * 16 + fr;
        const float bv = bias[n];
#pragma unroll
        for (int i = 0; i < 8; ++i) {
            const int m0 = bm + (i >> 2) * 128 + wm * 64 + (i & 3) * 16 + fq * 4;
            f32x4 a = acc[i][j];
            if (n < D) {
#pragma unroll
                for (int r = 0; r < 4; ++r)
                    Qb[(size_t)(m0 + r) * D + n] = f2bf((a[r] + bv) * qscale);
            } else if (n < 2 * D) {
#pragma unroll
                for (int r = 0; r < 4; ++r)
                    Kb[(size_t)(m0 + r) * D + (n - D)] = f2bf(a[r] + bv);
            } else {
                const int h = (n - 2 * D) >> 7;
                const int dh = (n - 2 * D) & 127;
                const int bb = m0 >> 9;
                const int t = m0 & 511;
                ushort4 pk;
                pk.x = f2bf(a[0] + bv); pk.y = f2bf(a[1] + bv);
                pk.z = f2bf(a[2] + bv); pk.w = f2bf(a[3] + bv);
                *(ushort4*)&Vt[((size_t)(bb * H + h) * DH + dh) * TL + t] = pk;
            }
        }
    }
}

// ---------------- MFMA flash attention -------------------------------------
#define LSW16(r, g) ((((r) << 4) + ((g) ^ ((r) & 7))) << 3)
#define LSW8(r, g) ((((r) << 3) + ((g) ^ ((r) & 7))) << 3)

__global__ __launch_bounds__(256, 2) void attn_mfma(
    const ushort_t* __restrict__ Qb, const ushort_t* __restrict__ Kb,
    const ushort_t* __restrict__ Vt, ushort_t* __restrict__ Ab) {
    __shared__ ushort_t Qs[64 * 128];
    __shared__ ushort_t Ks[64 * 128];
    __shared__ ushort_t Vts[128 * 64];
    __shared__ ushort_t Ps[64 * 72];

    const int q0 = blockIdx.x * 64;
    const int bh = blockIdx.y;
    const int b = bh >> 3;
    const int h = bh & 7;
    const int tid = threadIdx.x;
    const int lane = tid & 63;
    const int w = tid >> 6;
    const int fr = lane & 15;
    const int fq = lane >> 4;

    const float slope = exp2f(-(float)(h + 1));

#pragma unroll
    for (int kk = 0; kk < 4; ++kk) {
        int s = tid + kk * 256;
        int r = s >> 4, gp = s & 15, gl = gp ^ (r & 7);
        gload_lds16(Qb + (size_t)(b * TL + q0 + r) * D + h * DH + gl * 8,
                    &Qs[s * 8]);
    }

    f32x4 o8[8];
    float m_i[4], l_i[4];
#pragma unroll
    for (int nt = 0; nt < 8; ++nt) o8[nt] = (f32x4){0.f, 0.f, 0.f, 0.f};
#pragma unroll
    for (int r = 0; r < 4; ++r) { m_i[r] = -1e30f; l_i[r] = 0.f; }

    for (int kt = 0; kt < TL / 64; ++kt) {
        __syncthreads();
#pragma unroll
        for (int kk = 0; kk < 4; ++kk) {
            int s = tid + kk * 256;
            int r = s >> 4, gp = s & 15, gl = gp ^ (r & 7);
            gload_lds16(Kb + (size_t)(b * TL + kt * 64 + r) * D + h * DH + gl * 8,
                        &Ks[s * 8]);
        }
#pragma unroll
        for (int kk = 0; kk < 4; ++kk) {
            int s = tid + kk * 256;
            int r = s >> 3, gp = s & 7, gl = gp ^ (r & 7);
            gload_lds16(Vt + ((size_t)bh * DH + r) * TL + kt * 64 + gl * 8,
                        &Vts[s * 8]);
        }
        __syncthreads();

        f32x4 sacc[4];
#pragma unroll
        for (int jt = 0; jt < 4; ++jt) sacc[jt] = (f32x4){0.f, 0.f, 0.f, 0.f};
        __builtin_amdgcn_s_setprio(1);
#pragma unroll
        for (int s4 = 0; s4 < 4; ++s4) {
            bf16x8 aq = *(const bf16x8*)&Qs[LSW16(w * 16 + fr, s4 * 4 + fq)];
#pragma unroll
            for (int jt = 0; jt < 4; ++jt) {
                bf16x8 kb = *(const bf16x8*)&Ks[LSW16(jt * 16 + fr, s4 * 4 + fq)];
                sacc[jt] = __builtin_amdgcn_mfma_f32_16x16x32_bf16(
                    aq, kb, sacc[jt], 0, 0, 0);
            }
        }
        __builtin_amdgcn_s_setprio(0);

        const int iq = q0 + w * 16 + fq * 4;
        const int jk = kt * 64 + fr;
        float al[4];
#pragma unroll
        for (int r = 0; r < 4; ++r) {
            float sv[4];
#pragma unroll
            for (int jt = 0; jt < 4; ++jt)
                sv[jt] = sacc[jt][r] -
                         slope * fabsf((float)(iq + r - jk - jt * 16));
            float mx = fmaxf(fmaxf(sv[0], sv[1]), fmaxf(sv[2], sv[3]));
            mx = fmaxf(mx, __shfl_xor(mx, 1));
            mx = fmaxf(mx, __shfl_xor(mx, 2));
            mx = fmaxf(mx, __shfl_xor(mx, 4));
            mx = fmaxf(mx, __shfl_xor(mx, 8));
            float mnew = fmaxf(m_i[r], mx);
            al[r] = __expf(m_i[r] - mnew);
            float rs = 0.f;
#pragma unroll
            for (int jt = 0; jt < 4; ++jt) {
                sv[jt] = __expf(sv[jt] - mnew);
                rs += sv[jt];
            }
            rs += __shfl_xor(rs, 1);
            rs += __shfl_xor(rs, 2);
            rs += __shfl_xor(rs, 4);
            rs += __shfl_xor(rs, 8);
            l_i[r] = l_i[r] * al[r] + rs;
            m_i[r] = mnew;
            const int prow = w * 16 + fq * 4 + r;
#pragma unroll
            for (int jt = 0; jt < 4; ++jt)
                Ps[prow * 72 + jt * 16 + fr] = f2bf(sv[jt]);
        }
#pragma unroll
        for (int nt = 0; nt < 8; ++nt)
#pragma unroll
            for (int r = 0; r < 4; ++r) o8[nt][r] *= al[r];

        __builtin_amdgcn_s_setprio(1);
#pragma unroll
        for (int s2 = 0; s2 < 2; ++s2) {
            bf16x8 pa = *(const bf16x8*)&Ps[(w * 16 + fr) * 72 + s2 * 32 + fq * 8];
#pragma unroll
            for (int nt = 0; nt < 8; ++nt) {
                bf16x8 vb = *(const bf16x8*)&Vts[LSW8(nt * 16 + fr, s2 * 4 + fq)];
                o8[nt] = __builtin_amdgcn_mfma_f32_16x16x32_bf16(
                    pa, vb, o8[nt], 0, 0, 0);
            }
        }
        __builtin_amdgcn_s_setprio(0);
    }

#pragma unroll
    for (int r = 0; r < 4; ++r) {
        float inv = 1.f / l_i[r];
        const size_t base = (size_t)(b * TL + q0 + w * 16 + fq * 4 + r) * D + h * DH;
#pragma unroll
        for (int nt = 0; nt < 8; ++nt)
            Ab[base + nt * 16 + fr] = f2bf(o8[nt][r] * inv);
    }
}

// ---------------- fused residual + LayerNorm, one wave per row -------------
__global__ __launch_bounds__(256) void add_ln(const float* __restrict__ x,
                                              const float* __restrict__ y,
                                              const float* __restrict__ g,
                                              const float* __restrict__ bta,
                                              float* __restrict__ out,
                                              ushort_t* __restrict__ outb) {
    const int row = blockIdx.x * 4 + (threadIdx.x >> 6);
    const int lane = threadIdx.x & 63;
    const size_t rbase = (size_t)row * D;

    float4 v[4];
#pragma unroll
    for (int j = 0; j < 4; ++j) {
        float4 xv = *(const float4*)(x + rbase + lane * 4 + j * 256);
        float4 yv = *(const float4*)(y + rbase + lane * 4 + j * 256);
        v[j].x = xv.x + yv.x; v[j].y = xv.y + yv.y;
        v[j].z = xv.z + yv.z; v[j].w = xv.w + yv.w;
    }

    float s = 0.f;
#pragma unroll
    for (int j = 0; j < 4; ++j) s += v[j].x + v[j].y + v[j].z + v[j].w;
#pragma unroll
    for (int off = 32; off; off >>= 1) s += __shfl_xor(s, off);
    const float mean = s * (1.f / (float)D);

    float sq = 0.f;
#pragma unroll
    for (int j = 0; j < 4; ++j) {
        float d0 = v[j].x - mean, d1 = v[j].y - mean;
        float d2 = v[j].z - mean, d3 = v[j].w - mean;
        sq += d0 * d0 + d1 * d1 + d2 * d2 + d3 * d3;
    }
#pragma unroll
    for (int off = 32; off; off >>= 1) sq += __shfl_xor(sq, off);
    const float var = sq * (1.f / (float)D);
    const float inv = rsqrtf(var + 1e-5f);

#pragma unroll
    for (int j = 0; j < 4; ++j) {
        const int col = lane * 4 + j * 256;
        float4 gv = *(const float4*)(g + col);
        float4 bv = *(const float4*)(bta + col);
        float4 o;
        o.x = (v[j].x - mean) * inv * gv.x + bv.x;
        o.y = (v[j].y - mean) * inv * gv.y + bv.y;
        o.z = (v[j].z - mean) * inv * gv.z + bv.z;
        o.w = (v[j].w - mean) * inv * gv.w + bv.w;
        *(float4*)(out + rbase + col) = o;
        ushort4 ob;
        ob.x = f2bf(o.x); ob.y = f2bf(o.y); ob.z = f2bf(o.z); ob.w = f2bf(o.w);
        *(ushort4*)(outb + rbase + col) = ob;
    }
}

// ---------------- launcher -------------------------------------------------
extern "C" void kernel_launch(void* const* d_in, const int* in_sizes, int n_in,
                              void* d_out, int out_size, void* d_ws, size_t ws_size,
                              hipStream_t stream) {
    const float* x_in   = (const float*)d_in[0];
    const float* pre_w  = (const float*)d_in[1];
    const float* pre_b  = (const float*)d_in[2];
    const float* in_w   = (const float*)d_in[3];
    const float* in_b   = (const float*)d_in[4];
    const float* out_w  = (const float*)d_in[5];
    const float* out_b  = (const float*)d_in[6];
    const float* ln1_g  = (const float*)d_in[7];
    const float* ln1_b  = (const float*)d_in[8];
    const float* ff1_w  = (const float*)d_in[9];
    const float* ff1_b  = (const float*)d_in[10];
    const float* ff2_w  = (const float*)d_in[11];
    const float* ff2_b  = (const float*)d_in[12];
    const float* ln2_g  = (const float*)d_in[13];
    const float* ln2_b  = (const float*)d_in[14];
    const float* post_w = (const float*)d_in[15];
    const float* post_b = (const float*)d_in[16];

    static bool attr_set = false;
    if (!attr_set) {
        hipFuncSetAttribute((const void*)gemm_qkv256,
                            hipFuncAttributeMaxDynamicSharedMemorySize, 131072);
        hipFuncSetAttribute((const void*)gemm_n128,
                            hipFuncAttributeMaxDynamicSharedMemorySize, 65536);
        attr_set = true;
    }

    float* X = (float*)d_ws;
    float* Y = X + (size_t)M_ROWS * D;
    ushort_t* Xb   = (ushort_t*)(Y + (size_t)M_ROWS * D);
    ushort_t* Ab   = Xb + (size_t)M_ROWS * D;
    ushort_t* Qb   = Ab + (size_t)M_ROWS * D;
    ushort_t* Kb   = Qb + (size_t)M_ROWS * D;
    ushort_t* Vt   = Kb + (size_t)M_ROWS * D;
    ushort_t* xinb = Vt + (size_t)M_ROWS * D;
    ushort_t* pwb  = xinb + (size_t)M_ROWS * 512;
    ushort_t* iwb  = pwb + (size_t)D * 512;
    ushort_t* owb  = iwb + (size_t)NL * 3 * D * D;
    ushort_t* f1wb = owb + (size_t)NL * D * D;
    ushort_t* f2wb = f1wb + (size_t)NL * DFF * D;
    ushort_t* powb = f2wb + (size_t)NL * D * DFF;

    const dim3 blk(256);

    CvtArgs ca;
    ca.s[0] = x_in;   ca.d[0] = xinb; ca.nq[0] = (M_ROWS * 512) / 4;
    ca.s[1] = pre_w;  ca.d[1] = pwb;  ca.nq[1] = (D * 512) / 4;
    ca.s[2] = in_w;   ca.d[2] = iwb;  ca.nq[2] = (NL * 3 * D * D) / 4;
    ca.s[3] = out_w;  ca.d[3] = owb;  ca.nq[3] = (NL * D * D) / 4;
    ca.s[4] = ff1_w;  ca.d[4] = f1wb; ca.nq[4] = (NL * DFF * D) / 4;
    ca.s[5] = ff2_w;  ca.d[5] = f2wb; ca.nq[5] = (NL * D * DFF) / 4;
    ca.s[6] = post_w; ca.d[6] = powb; ca.nq[6] = (D * D) / 4;
    {
        long long total = 0;
        for (int i = 0; i < 7; ++i) total += ca.nq[i];
        long long cum = 0;
        ca.bstart[0] = 0;
        for (int i = 0; i < 7; ++i) {
            cum += ca.nq[i];
            ca.bstart[i + 1] = (int)((cum * 4096) / total);
        }
        ca.bstart[7] = 4096;
    }
    cvt_all<<<4096, blk, 0, stream>>>(ca);

    const dim3 gN128(D / 128, M_ROWS / 128);        // 256 blocks, 512 thr

    gemm_n128<<<gN128, dim3(512), 65536, stream>>>(xinb, pwb, pre_b, X, Xb,
                                                   M_ROWS, D, 512, 0);

    for (int l = 0; l < NL; ++l) {
        gemm_qkv256<<<dim3(192), dim3(512), 131072, stream>>>(
            Xb, iwb + (size_t)l * 3 * D * D, in_b + (size_t)l * 3 * D,
            Qb, Kb, Vt);
        attn_mfma<<<dim3(TL / 64, B * H), blk, 0, stream>>>(Qb, Kb, Vt, Ab);
        gemm_n128<<<gN128, dim3(512), 65536, stream>>>(
            Ab, owb + (size_t)l * D * D, out_b + (size_t)l * D, Y, nullptr,
            M_ROWS, D, D, 0);
        add_ln<<<dim3(M_ROWS / 4), blk, 0, stream>>>(X, Y, ln1_g + (size_t)l * D,
                                                     ln1_b + (size_t)l * D, X, Xb);
        gemm_n128<<<gN128, dim3(512), 65536, stream>>>(
            Xb, f1wb + (size_t)l * DFF * D, ff1_b + (size_t)l * DFF, nullptr, Ab,
            M_ROWS, DFF, D, 1);
        gemm_n128<<<gN128, dim3(512), 65536, stream>>>(
            Ab, f2wb + (size_t)l * D * DFF, ff2_b + (size_t)l * D, Y, nullptr,
            M_ROWS, D, DFF, 0);
        add_ln<<<dim3(M_ROWS / 4), blk, 0, stream>>>(X, Y, ln2_g + (size_t)l * D,
                                                     ln2_b + (size_t)l * D, X, Xb);
    }

    gemm_n128<<<gN128, dim3(512), 65536, stream>>>(Xb, powb, post_b,
                                                   (float*)d_out, nullptr,
                                                   M_ROWS, D, D, 0);
}

// Round 5
// 1077.519 us; speedup vs baseline: 1.1962x; 1.0457x over previous
//
#include <hip/hip_runtime.h>
#include <hip/hip_bf16.h>

// ---------------- problem constants ----------------
#define B 8
#define TL 512
#define M_ROWS 4096
#define D 1024
#define DFF 1024
#define H 8
#define DH 128
#define NL 6

typedef unsigned short ushort_t;
typedef unsigned int uint_t;
typedef short bf16x8 __attribute__((ext_vector_type(8)));
typedef float f32x4 __attribute__((ext_vector_type(4)));

__device__ __forceinline__ ushort_t f2bf(float f) {
    uint_t u = __float_as_uint(f);
    u += 0x7FFFu + ((u >> 16) & 1u);
    return (ushort_t)(u >> 16);
}
__device__ __forceinline__ float gelu_exact(float x) {
    return 0.5f * x * (1.0f + erff(x * 0.70710678118654752f));
}
__device__ __forceinline__ void gload_lds16(const ushort_t* g, ushort_t* l) {
    __builtin_amdgcn_global_load_lds(
        (const __attribute__((address_space(1))) void*)g,
        (__attribute__((address_space(3))) void*)l, 16, 0, 0);
}

// ---------------- f32 -> bf16 conversion, block-partitioned ----------------
struct CvtArgs {
    const float* s[7];
    ushort_t* d[7];
    int nq[7];      // float4-chunk counts
    int bstart[8];  // block ranges per segment
};

__global__ __launch_bounds__(256) void cvt_all(CvtArgs a) {
    const int bid = blockIdx.x;
#pragma unroll
    for (int seg = 0; seg < 7; ++seg) {
        const int b0 = a.bstart[seg], b1 = a.bstart[seg + 1];
        if (bid < b0 || bid >= b1) continue;
        const int stride = (b1 - b0) * 256;
        const float* s = a.s[seg];
        ushort_t* d = a.d[seg];
        const int nq = a.nq[seg];
        for (int i = (bid - b0) * 256 + threadIdx.x; i < nq; i += stride) {
            float4 v = *(const float4*)(s + (size_t)i * 4);
            ushort4 o;
            o.x = f2bf(v.x); o.y = f2bf(v.y); o.z = f2bf(v.z); o.w = f2bf(v.w);
            *(ushort4*)(d + (size_t)i * 4) = o;
        }
    }
}

// LDS row = 8 chunks of 16B (BK=64 bf16); XOR swizzle baked into staging.
#define LSLOT64(r, c) (((r) * 8 + ((c) ^ ((r) & 7))) * 8)

// ======== shared 128x128 pipelined K-loop machinery (3-buf, vmcnt(4)) ======
// 512 threads = 8 waves (2M x 4N); per-wave 64x32 out = acc[4][2].
// LDS: 3 bufs x 32 KB (A 16 KB + B 16 KB); buf i at ushort offset i*16384.
// Pipeline: stage t, t+1 in prologue; iter t: wait vmcnt(4) [t landed,
// t+1 in flight] -> barrier -> MFMA(t) -> issue stage(t+2). Never drains
// mid-loop (T3/T4); setprio(1) around MFMA cluster (T5).
#define PIPE_K_LOOP(NT)                                                        \
    {                                                                          \
        stage(0, 0);                                                           \
        stage(1, 64);                                                          \
        int bsel = 0;                                                          \
        for (int t = 0; t < (NT)-1; ++t) {                                     \
            asm volatile("s_waitcnt vmcnt(4)" ::: "memory");                   \
            __builtin_amdgcn_s_barrier();                                      \
            comp(bsel);                                                        \
            if (t + 2 < (NT)) {                                                \
                int nb = bsel + 2; if (nb >= 3) nb -= 3;                       \
                stage(nb, (t + 2) * 64);                                       \
            }                                                                  \
            ++bsel; if (bsel == 3) bsel = 0;                                   \
        }                                                                      \
        asm volatile("s_waitcnt vmcnt(0)" ::: "memory");                       \
        __builtin_amdgcn_s_barrier();                                          \
        comp(bsel);                                                            \
    }

// ---------------- N GEMM: 128x128 tile, BK=64, 3-buf pipeline --------------
__global__ __launch_bounds__(512) void gemm_n128(
    const ushort_t* __restrict__ A, const ushort_t* __restrict__ W,
    const float* __restrict__ bias, float* __restrict__ Cf,
    ushort_t* __restrict__ Cb, int M, int N, int K, int do_gelu) {
    extern __shared__ ushort_t lds[];

    const int tid = threadIdx.x;
    const int lane = tid & 63;
    const int w = tid >> 6;    // 0..7
    const int wm = w >> 2;     // 0..1 -> 64-row half
    const int wn = w & 3;      // 0..3 -> 32-col strip
    const int bm = blockIdx.y * 128;
    const int bn = blockIdx.x * 128;
    const int fr = lane & 15;
    const int fq = lane >> 4;

    const ushort_t* gA[2];
    const ushort_t* gB[2];
    int sdst[2];
#pragma unroll
    for (int u = 0; u < 2; ++u) {
        int s = tid + u * 512;
        int r = s >> 3, c = (s & 7) ^ (r & 7);
        gA[u] = A + (size_t)(bm + r) * K + c * 8;
        gB[u] = W + (size_t)(bn + r) * K + c * 8;
        sdst[u] = s * 8;
    }

    int aoff[4][2], boff[2][2];
#pragma unroll
    for (int ti = 0; ti < 4; ++ti)
#pragma unroll
        for (int ks = 0; ks < 2; ++ks)
            aoff[ti][ks] = LSLOT64(wm * 64 + ti * 16 + fr, ks * 4 + fq);
#pragma unroll
    for (int tj = 0; tj < 2; ++tj)
#pragma unroll
        for (int ks = 0; ks < 2; ++ks)
            boff[tj][ks] = LSLOT64(wn * 32 + tj * 16 + fr, ks * 4 + fq);

    f32x4 acc[4][2];
#pragma unroll
    for (int i = 0; i < 4; ++i)
#pragma unroll
        for (int j = 0; j < 2; ++j) acc[i][j] = (f32x4){0.f, 0.f, 0.f, 0.f};

    auto stage = [&](int buf, int k0) {
#pragma unroll
        for (int u = 0; u < 2; ++u)
            gload_lds16(gA[u] + k0, &lds[buf * 16384 + sdst[u]]);
#pragma unroll
        for (int u = 0; u < 2; ++u)
            gload_lds16(gB[u] + k0, &lds[buf * 16384 + 8192 + sdst[u]]);
    };
    auto comp = [&](int buf) {
#pragma unroll
        for (int ks = 0; ks < 2; ++ks) {
            bf16x8 af[4], bfv[2];
#pragma unroll
            for (int ti = 0; ti < 4; ++ti)
                af[ti] = *(const bf16x8*)&lds[buf * 16384 + aoff[ti][ks]];
#pragma unroll
            for (int tj = 0; tj < 2; ++tj)
                bfv[tj] = *(const bf16x8*)&lds[buf * 16384 + 8192 + boff[tj][ks]];
            __builtin_amdgcn_s_setprio(1);
#pragma unroll
            for (int i = 0; i < 4; ++i)
#pragma unroll
                for (int j = 0; j < 2; ++j)
                    acc[i][j] = __builtin_amdgcn_mfma_f32_16x16x32_bf16(
                        af[i], bfv[j], acc[i][j], 0, 0, 0);
            __builtin_amdgcn_s_setprio(0);
        }
    };

    const int NT = K >> 6;
    PIPE_K_LOOP(NT)
    __syncthreads();  // all reads done before eps overlays buffers

    // ---- epilogue: LDS transpose to wide stores ----
    float bv[2];
#pragma unroll
    for (int tj = 0; tj < 2; ++tj) bv[tj] = bias[bn + wn * 32 + tj * 16 + fr];

    float* eps = (float*)lds;  // [64][132] f32 = 33.8 KB
#pragma unroll
    for (int p = 0; p < 2; ++p) {
        if (p) __syncthreads();
        if (wm == p) {
#pragma unroll
            for (int ti = 0; ti < 4; ++ti)
#pragma unroll
                for (int tj = 0; tj < 2; ++tj)
#pragma unroll
                    for (int r = 0; r < 4; ++r) {
                        float v = acc[ti][tj][r] + bv[tj];
                        if (do_gelu) v = gelu_exact(v);
                        eps[(ti * 16 + fq * 4 + r) * 132 +
                            wn * 32 + tj * 16 + fr] = v;
                    }
        }
        __syncthreads();
#pragma unroll
        for (int k = 0; k < 4; ++k) {
            int f = tid + k * 512;        // 0..2047
            int row = f >> 5, c4 = f & 31;
            float4 v = *(const float4*)&eps[row * 132 + c4 * 4];
            const size_t off = (size_t)(bm + p * 64 + row) * N + bn + c4 * 4;
            if (Cf) *(float4*)(Cf + off) = v;
            if (Cb) {
                ushort4 ob;
                ob.x = f2bf(v.x); ob.y = f2bf(v.y);
                ob.z = f2bf(v.z); ob.w = f2bf(v.w);
                *(ushort4*)(Cb + off) = ob;
            }
        }
    }
}

// ---------------- QKV GEMM: 128x128 tile, 3-buf pipeline, 768 blocks -------
// Region is per-block uniform: bx<8 -> Q, bx<16 -> K, else V (transposed).
__global__ __launch_bounds__(512) void gemm_qkv128(
    const ushort_t* __restrict__ A, const ushort_t* __restrict__ W,
    const float* __restrict__ bias, ushort_t* __restrict__ Qb,
    ushort_t* __restrict__ Kb, ushort_t* __restrict__ Vt) {
    extern __shared__ ushort_t lds[];
    const int K = 1024;

    // XCD-chunked bijective swizzle: 768 = 8 XCDs x 96 (4 by-rows x 24 bx)
    const int bid = blockIdx.x;
    const int wg = (bid & 7) * 96 + (bid >> 3);
    const int by = wg / 24, bx = wg - by * 24;
    const int bm = by * 128, bn = bx * 128;

    const int tid = threadIdx.x;
    const int lane = tid & 63;
    const int w = tid >> 6;
    const int wm = w >> 2;
    const int wn = w & 3;
    const int fr = lane & 15;
    const int fq = lane >> 4;

    const ushort_t* gA[2];
    const ushort_t* gB[2];
    int sdst[2];
#pragma unroll
    for (int u = 0; u < 2; ++u) {
        int s = tid + u * 512;
        int r = s >> 3, c = (s & 7) ^ (r & 7);
        gA[u] = A + (size_t)(bm + r) * K + c * 8;
        gB[u] = W + (size_t)(bn + r) * K + c * 8;
        sdst[u] = s * 8;
    }

    int aoff[4][2], boff[2][2];
#pragma unroll
    for (int ti = 0; ti < 4; ++ti)
#pragma unroll
        for (int ks = 0; ks < 2; ++ks)
            aoff[ti][ks] = LSLOT64(wm * 64 + ti * 16 + fr, ks * 4 + fq);
#pragma unroll
    for (int tj = 0; tj < 2; ++tj)
#pragma unroll
        for (int ks = 0; ks < 2; ++ks)
            boff[tj][ks] = LSLOT64(wn * 32 + tj * 16 + fr, ks * 4 + fq);

    f32x4 acc[4][2];
#pragma unroll
    for (int i = 0; i < 4; ++i)
#pragma unroll
        for (int j = 0; j < 2; ++j) acc[i][j] = (f32x4){0.f, 0.f, 0.f, 0.f};

    auto stage = [&](int buf, int k0) {
#pragma unroll
        for (int u = 0; u < 2; ++u)
            gload_lds16(gA[u] + k0, &lds[buf * 16384 + sdst[u]]);
#pragma unroll
        for (int u = 0; u < 2; ++u)
            gload_lds16(gB[u] + k0, &lds[buf * 16384 + 8192 + sdst[u]]);
    };
    auto comp = [&](int buf) {
#pragma unroll
        for (int ks = 0; ks < 2; ++ks) {
            bf16x8 af[4], bfv[2];
#pragma unroll
            for (int ti = 0; ti < 4; ++ti)
                af[ti] = *(const bf16x8*)&lds[buf * 16384 + aoff[ti][ks]];
#pragma unroll
            for (int tj = 0; tj < 2; ++tj)
                bfv[tj] = *(const bf16x8*)&lds[buf * 16384 + 8192 + boff[tj][ks]];
            __builtin_amdgcn_s_setprio(1);
#pragma unroll
            for (int i = 0; i < 4; ++i)
#pragma unroll
                for (int j = 0; j < 2; ++j)
                    acc[i][j] = __builtin_amdgcn_mfma_f32_16x16x32_bf16(
                        af[i], bfv[j], acc[i][j], 0, 0, 0);
            __builtin_amdgcn_s_setprio(0);
        }
    };

    PIPE_K_LOOP(16)

    const float qscale = 0.08838834764831845f;
    float bv[2];
#pragma unroll
    for (int tj = 0; tj < 2; ++tj) bv[tj] = bias[bn + wn * 32 + tj * 16 + fr];

    if (bn < 2 * D) {
        // Q/K: LDS-transpose epilogue, wide bf16 stores
        __syncthreads();
        const float scale = (bn < D) ? qscale : 1.f;
        ushort_t* dst = (bn < D) ? Qb : Kb;
        const int nc0 = (bn < D) ? bn : bn - D;
        float* eps = (float*)lds;  // [64][132]
#pragma unroll
        for (int p = 0; p < 2; ++p) {
            if (p) __syncthreads();
            if (wm == p) {
#pragma unroll
                for (int ti = 0; ti < 4; ++ti)
#pragma unroll
                    for (int tj = 0; tj < 2; ++tj)
#pragma unroll
                        for (int r = 0; r < 4; ++r)
                            eps[(ti * 16 + fq * 4 + r) * 132 +
                                wn * 32 + tj * 16 + fr] =
                                (acc[ti][tj][r] + bv[tj]) * scale;
            }
            __syncthreads();
#pragma unroll
            for (int k = 0; k < 4; ++k) {
                int f = tid + k * 512;
                int row = f >> 5, c4 = f & 31;
                float4 v = *(const float4*)&eps[row * 132 + c4 * 4];
                ushort4 ob;
                ob.x = f2bf(v.x); ob.y = f2bf(v.y);
                ob.z = f2bf(v.z); ob.w = f2bf(v.w);
                *(ushort4*)(dst + (size_t)(bm + p * 64 + row) * D + nc0 +
                            c4 * 4) = ob;
            }
        }
    } else {
        // V: direct transposed store (8B contiguous along t)
#pragma unroll
        for (int tj = 0; tj < 2; ++tj) {
            const int n = bn + wn * 32 + tj * 16 + fr;
            const int h = (n - 2 * D) >> 7;
            const int dh = (n - 2 * D) & 127;
#pragma unroll
            for (int ti = 0; ti < 4; ++ti) {
                const int m0 = bm + wm * 64 + ti * 16 + fq * 4;
                const int bb = m0 >> 9;
                const int t = m0 & 511;
                f32x4 a = acc[ti][tj];
                ushort4 pk;
                pk.x = f2bf(a[0] + bv[tj]); pk.y = f2bf(a[1] + bv[tj]);
                pk.z = f2bf(a[2] + bv[tj]); pk.w = f2bf(a[3] + bv[tj]);
                *(ushort4*)&Vt[((size_t)(bb * H + h) * DH + dh) * TL + t] = pk;
            }
        }
    }
}

// ---------------- MFMA flash attention -------------------------------------
#define LSW16(r, g) ((((r) << 4) + ((g) ^ ((r) & 7))) << 3)
#define LSW8(r, g) ((((r) << 3) + ((g) ^ ((r) & 7))) << 3)

__global__ __launch_bounds__(256, 2) void attn_mfma(
    const ushort_t* __restrict__ Qb, const ushort_t* __restrict__ Kb,
    const ushort_t* __restrict__ Vt, ushort_t* __restrict__ Ab) {
    __shared__ ushort_t Qs[64 * 128];
    __shared__ ushort_t Ks[64 * 128];
    __shared__ ushort_t Vts[128 * 64];
    __shared__ ushort_t Ps[64 * 72];

    const int q0 = blockIdx.x * 64;
    const int bh = blockIdx.y;
    const int b = bh >> 3;
    const int h = bh & 7;
    const int tid = threadIdx.x;
    const int lane = tid & 63;
    const int w = tid >> 6;
    const int fr = lane & 15;
    const int fq = lane >> 4;

    const float slope = exp2f(-(float)(h + 1));

#pragma unroll
    for (int kk = 0; kk < 4; ++kk) {
        int s = tid + kk * 256;
        int r = s >> 4, gp = s & 15, gl = gp ^ (r & 7);
        gload_lds16(Qb + (size_t)(b * TL + q0 + r) * D + h * DH + gl * 8,
                    &Qs[s * 8]);
    }

    f32x4 o8[8];
    float m_i[4], l_i[4];
#pragma unroll
    for (int nt = 0; nt < 8; ++nt) o8[nt] = (f32x4){0.f, 0.f, 0.f, 0.f};
#pragma unroll
    for (int r = 0; r < 4; ++r) { m_i[r] = -1e30f; l_i[r] = 0.f; }

    for (int kt = 0; kt < TL / 64; ++kt) {
        __syncthreads();
#pragma unroll
        for (int kk = 0; kk < 4; ++kk) {
            int s = tid + kk * 256;
            int r = s >> 4, gp = s & 15, gl = gp ^ (r & 7);
            gload_lds16(Kb + (size_t)(b * TL + kt * 64 + r) * D + h * DH + gl * 8,
                        &Ks[s * 8]);
        }
#pragma unroll
        for (int kk = 0; kk < 4; ++kk) {
            int s = tid + kk * 256;
            int r = s >> 3, gp = s & 7, gl = gp ^ (r & 7);
            gload_lds16(Vt + ((size_t)bh * DH + r) * TL + kt * 64 + gl * 8,
                        &Vts[s * 8]);
        }
        __syncthreads();

        f32x4 sacc[4];
#pragma unroll
        for (int jt = 0; jt < 4; ++jt) sacc[jt] = (f32x4){0.f, 0.f, 0.f, 0.f};
        __builtin_amdgcn_s_setprio(1);
#pragma unroll
        for (int s4 = 0; s4 < 4; ++s4) {
            bf16x8 aq = *(const bf16x8*)&Qs[LSW16(w * 16 + fr, s4 * 4 + fq)];
#pragma unroll
            for (int jt = 0; jt < 4; ++jt) {
                bf16x8 kb = *(const bf16x8*)&Ks[LSW16(jt * 16 + fr, s4 * 4 + fq)];
                sacc[jt] = __builtin_amdgcn_mfma_f32_16x16x32_bf16(
                    aq, kb, sacc[jt], 0, 0, 0);
            }
        }
        __builtin_amdgcn_s_setprio(0);

        const int iq = q0 + w * 16 + fq * 4;
        const int jk = kt * 64 + fr;
        float al[4];
#pragma unroll
        for (int r = 0; r < 4; ++r) {
            float sv[4];
#pragma unroll
            for (int jt = 0; jt < 4; ++jt)
                sv[jt] = sacc[jt][r] -
                         slope * fabsf((float)(iq + r - jk - jt * 16));
            float mx = fmaxf(fmaxf(sv[0], sv[1]), fmaxf(sv[2], sv[3]));
            mx = fmaxf(mx, __shfl_xor(mx, 1));
            mx = fmaxf(mx, __shfl_xor(mx, 2));
            mx = fmaxf(mx, __shfl_xor(mx, 4));
            mx = fmaxf(mx, __shfl_xor(mx, 8));
            float mnew = fmaxf(m_i[r], mx);
            al[r] = __expf(m_i[r] - mnew);
            float rs = 0.f;
#pragma unroll
            for (int jt = 0; jt < 4; ++jt) {
                sv[jt] = __expf(sv[jt] - mnew);
                rs += sv[jt];
            }
            rs += __shfl_xor(rs, 1);
            rs += __shfl_xor(rs, 2);
            rs += __shfl_xor(rs, 4);
            rs += __shfl_xor(rs, 8);
            l_i[r] = l_i[r] * al[r] + rs;
            m_i[r] = mnew;
            const int prow = w * 16 + fq * 4 + r;
#pragma unroll
            for (int jt = 0; jt < 4; ++jt)
                Ps[prow * 72 + jt * 16 + fr] = f2bf(sv[jt]);
        }
#pragma unroll
        for (int nt = 0; nt < 8; ++nt)
#pragma unroll
            for (int r = 0; r < 4; ++r) o8[nt][r] *= al[r];

        __builtin_amdgcn_s_setprio(1);
#pragma unroll
        for (int s2 = 0; s2 < 2; ++s2) {
            bf16x8 pa = *(const bf16x8*)&Ps[(w * 16 + fr) * 72 + s2 * 32 + fq * 8];
#pragma unroll
            for (int nt = 0; nt < 8; ++nt) {
                bf16x8 vb = *(const bf16x8*)&Vts[LSW8(nt * 16 + fr, s2 * 4 + fq)];
                o8[nt] = __builtin_amdgcn_mfma_f32_16x16x32_bf16(
                    pa, vb, o8[nt], 0, 0, 0);
            }
        }
        __builtin_amdgcn_s_setprio(0);
    }

#pragma unroll
    for (int r = 0; r < 4; ++r) {
        float inv = 1.f / l_i[r];
        const size_t base = (size_t)(b * TL + q0 + w * 16 + fq * 4 + r) * D + h * DH;
#pragma unroll
        for (int nt = 0; nt < 8; ++nt)
            Ab[base + nt * 16 + fr] = f2bf(o8[nt][r] * inv);
    }
}

// ---------------- fused residual + LayerNorm, one wave per row -------------
__global__ __launch_bounds__(256) void add_ln(const float* __restrict__ x,
                                              const float* __restrict__ y,
                                              const float* __restrict__ g,
                                              const float* __restrict__ bta,
                                              float* __restrict__ out,
                                              ushort_t* __restrict__ outb) {
    const int row = blockIdx.x * 4 + (threadIdx.x >> 6);
    const int lane = threadIdx.x & 63;
    const size_t rbase = (size_t)row * D;

    float4 v[4];
#pragma unroll
    for (int j = 0; j < 4; ++j) {
        float4 xv = *(const float4*)(x + rbase + lane * 4 + j * 256);
        float4 yv = *(const float4*)(y + rbase + lane * 4 + j * 256);
        v[j].x = xv.x + yv.x; v[j].y = xv.y + yv.y;
        v[j].z = xv.z + yv.z; v[j].w = xv.w + yv.w;
    }

    float s = 0.f;
#pragma unroll
    for (int j = 0; j < 4; ++j) s += v[j].x + v[j].y + v[j].z + v[j].w;
#pragma unroll
    for (int off = 32; off; off >>= 1) s += __shfl_xor(s, off);
    const float mean = s * (1.f / (float)D);

    float sq = 0.f;
#pragma unroll
    for (int j = 0; j < 4; ++j) {
        float d0 = v[j].x - mean, d1 = v[j].y - mean;
        float d2 = v[j].z - mean, d3 = v[j].w - mean;
        sq += d0 * d0 + d1 * d1 + d2 * d2 + d3 * d3;
    }
#pragma unroll
    for (int off = 32; off; off >>= 1) sq += __shfl_xor(sq, off);
    const float var = sq * (1.f / (float)D);
    const float inv = rsqrtf(var + 1e-5f);

#pragma unroll
    for (int j = 0; j < 4; ++j) {
        const int col = lane * 4 + j * 256;
        float4 gv = *(const float4*)(g + col);
        float4 bv = *(const float4*)(bta + col);
        float4 o;
        o.x = (v[j].x - mean) * inv * gv.x + bv.x;
        o.y = (v[j].y - mean) * inv * gv.y + bv.y;
        o.z = (v[j].z - mean) * inv * gv.z + bv.z;
        o.w = (v[j].w - mean) * inv * gv.w + bv.w;
        *(float4*)(out + rbase + col) = o;
        ushort4 ob;
        ob.x = f2bf(o.x); ob.y = f2bf(o.y); ob.z = f2bf(o.z); ob.w = f2bf(o.w);
        *(ushort4*)(outb + rbase + col) = ob;
    }
}

// ---------------- launcher -------------------------------------------------
extern "C" void kernel_launch(void* const* d_in, const int* in_sizes, int n_in,
                              void* d_out, int out_size, void* d_ws, size_t ws_size,
                              hipStream_t stream) {
    const float* x_in   = (const float*)d_in[0];
    const float* pre_w  = (const float*)d_in[1];
    const float* pre_b  = (const float*)d_in[2];
    const float* in_w   = (const float*)d_in[3];
    const float* in_b   = (const float*)d_in[4];
    const float* out_w  = (const float*)d_in[5];
    const float* out_b  = (const float*)d_in[6];
    const float* ln1_g  = (const float*)d_in[7];
    const float* ln1_b  = (const float*)d_in[8];
    const float* ff1_w  = (const float*)d_in[9];
    const float* ff1_b  = (const float*)d_in[10];
    const float* ff2_w  = (const float*)d_in[11];
    const float* ff2_b  = (const float*)d_in[12];
    const float* ln2_g  = (const float*)d_in[13];
    const float* ln2_b  = (const float*)d_in[14];
    const float* post_w = (const float*)d_in[15];
    const float* post_b = (const float*)d_in[16];

    static bool attr_set = false;
    if (!attr_set) {
        hipFuncSetAttribute((const void*)gemm_n128,
                            hipFuncAttributeMaxDynamicSharedMemorySize, 98304);
        hipFuncSetAttribute((const void*)gemm_qkv128,
                            hipFuncAttributeMaxDynamicSharedMemorySize, 98304);
        attr_set = true;
    }

    float* X = (float*)d_ws;
    float* Y = X + (size_t)M_ROWS * D;
    ushort_t* Xb   = (ushort_t*)(Y + (size_t)M_ROWS * D);
    ushort_t* Ab   = Xb + (size_t)M_ROWS * D;
    ushort_t* Qb   = Ab + (size_t)M_ROWS * D;
    ushort_t* Kb   = Qb + (size_t)M_ROWS * D;
    ushort_t* Vt   = Kb + (size_t)M_ROWS * D;
    ushort_t* xinb = Vt + (size_t)M_ROWS * D;
    ushort_t* pwb  = xinb + (size_t)M_ROWS * 512;
    ushort_t* iwb  = pwb + (size_t)D * 512;
    ushort_t* owb  = iwb + (size_t)NL * 3 * D * D;
    ushort_t* f1wb = owb + (size_t)NL * D * D;
    ushort_t* f2wb = f1wb + (size_t)NL * DFF * D;
    ushort_t* powb = f2wb + (size_t)NL * D * DFF;

    const dim3 blk(256);

    CvtArgs ca;
    ca.s[0] = x_in;   ca.d[0] = xinb; ca.nq[0] = (M_ROWS * 512) / 4;
    ca.s[1] = pre_w;  ca.d[1] = pwb;  ca.nq[1] = (D * 512) / 4;
    ca.s[2] = in_w;   ca.d[2] = iwb;  ca.nq[2] = (NL * 3 * D * D) / 4;
    ca.s[3] = out_w;  ca.d[3] = owb;  ca.nq[3] = (NL * D * D) / 4;
    ca.s[4] = ff1_w;  ca.d[4] = f1wb; ca.nq[4] = (NL * DFF * D) / 4;
    ca.s[5] = ff2_w;  ca.d[5] = f2wb; ca.nq[5] = (NL * D * DFF) / 4;
    ca.s[6] = post_w; ca.d[6] = powb; ca.nq[6] = (D * D) / 4;
    {
        long long total = 0;
        for (int i = 0; i < 7; ++i) total += ca.nq[i];
        long long cum = 0;
        ca.bstart[0] = 0;
        for (int i = 0; i < 7; ++i) {
            cum += ca.nq[i];
            ca.bstart[i + 1] = (int)((cum * 4096) / total);
        }
        ca.bstart[7] = 4096;
    }
    cvt_all<<<4096, blk, 0, stream>>>(ca);

    const dim3 gN128(D / 128, M_ROWS / 128);        // 256 blocks, 512 thr

    gemm_n128<<<gN128, dim3(512), 98304, stream>>>(xinb, pwb, pre_b, X, Xb,
                                                   M_ROWS, D, 512, 0);

    for (int l = 0; l < NL; ++l) {
        gemm_qkv128<<<dim3(768), dim3(512), 98304, stream>>>(
            Xb, iwb + (size_t)l * 3 * D * D, in_b + (size_t)l * 3 * D,
            Qb, Kb, Vt);
        attn_mfma<<<dim3(TL / 64, B * H), blk, 0, stream>>>(Qb, Kb, Vt, Ab);
        gemm_n128<<<gN128, dim3(512), 98304, stream>>>(
            Ab, owb + (size_t)l * D * D, out_b + (size_t)l * D, Y, nullptr,
            M_ROWS, D, D, 0);
        add_ln<<<dim3(M_ROWS / 4), blk, 0, stream>>>(X, Y, ln1_g + (size_t)l * D,
                                                     ln1_b + (size_t)l * D, X, Xb);
        gemm_n128<<<gN128, dim3(512), 98304, stream>>>(
            Xb, f1wb + (size_t)l * DFF * D, ff1_b + (size_t)l * DFF, nullptr, Ab,
            M_ROWS, DFF, D, 1);
        gemm_n128<<<gN128, dim3(512), 98304, stream>>>(
            Ab, f2wb + (size_t)l * D * DFF, ff2_b + (size_t)l * D, Y, nullptr,
            M_ROWS, D, DFF, 0);
        add_ln<<<dim3(M_ROWS / 4), blk, 0, stream>>>(X, Y, ln2_g + (size_t)l * D,
                                                     ln2_b + (size_t)l * D, X, Xb);
    }

    gemm_n128<<<gN128, dim3(512), 98304, stream>>>(Xb, powb, post_b,
                                                   (float*)d_out, nullptr,
                                                   M_ROWS, D, D, 0);
}